// Round 2
// baseline (757.060 us; speedup 1.0000x reference)
//
#include <hip/hip_runtime.h>

#define INV_QTR 0.59460355750136053f   // 8^(-1/4)

typedef _Float16 f16;
typedef _Float16 f16x8 __attribute__((ext_vector_type(8)));
typedef float f32x4 __attribute__((ext_vector_type(4)));

__device__ __forceinline__ void gload16(const void* g, void* l) {
    __builtin_amdgcn_global_load_lds(
        (const __attribute__((address_space(1))) void*)g,
        (__attribute__((address_space(3))) void*)l, 16, 0, 0);
}

// ---------------------------------------------------------------------------
// All-f16 BT-GEMM (m97 structure): dst[m][n] = sum_k X[m][k]*W[n][k] (+bias).
// M=16384, N=1024, K=1024. 128x128 tile, BK=64, global_load_lds width=16,
// XOR swizzle on 16B chunks, 16x16x32 f16 MFMA, fp32 accum.  (verified)
// ---------------------------------------------------------------------------
template <bool OF, bool BIAS>
__device__ __forceinline__ void gemm_f16_body(const f16* __restrict__ X,
                                              const f16* __restrict__ W,
                                              const float* __restrict__ bias,
                                              void* __restrict__ dst) {
    __shared__ __align__(16) f16 As[128 * 64];
    __shared__ __align__(16) f16 Bs[128 * 64];

    const int tid  = threadIdx.x;
    const int lane = tid & 63;
    const int wave = tid >> 6;
    const int m0   = blockIdx.x * 128;
    const int n0   = blockIdx.y * 128;
    const int wm   = (wave >> 1) * 64;
    const int wn   = (wave & 1) * 64;
    const int frow = lane & 15;
    const int quad = lane >> 4;

    f32x4 acc[4][4] = {};

    for (int k0 = 0; k0 < 1024; k0 += 64) {
        __syncthreads();
        #pragma unroll
        for (int i = 0; i < 4; ++i) {
            int slot = i * 256 + tid;
            int row  = slot >> 3;
            int sc   = slot & 7;
            int gc   = sc ^ (row & 7);
            gload16(X + (size_t)(m0 + row) * 1024 + k0 + gc * 8,
                    (char*)As + slot * 16);
            gload16(W + (size_t)(n0 + row) * 1024 + k0 + gc * 8,
                    (char*)Bs + slot * 16);
        }
        __syncthreads();

        #pragma unroll
        for (int kk = 0; kk < 2; ++kk) {
            f16x8 fa[4], fb[4];
            #pragma unroll
            for (int t = 0; t < 4; ++t) {
                int arow = wm + t * 16 + frow;
                int asc  = (kk * 4 + quad) ^ (arow & 7);
                fa[t] = *(const f16x8*)(As + arow * 64 + asc * 8);
                int brow = wn + t * 16 + frow;
                int bsc  = (kk * 4 + quad) ^ (brow & 7);
                fb[t] = *(const f16x8*)(Bs + brow * 64 + bsc * 8);
            }
            #pragma unroll
            for (int tm = 0; tm < 4; ++tm)
                #pragma unroll
                for (int tn = 0; tn < 4; ++tn)
                    acc[tm][tn] = __builtin_amdgcn_mfma_f32_16x16x32_f16(
                        fa[tm], fb[tn], acc[tm][tn], 0, 0, 0);
        }
    }

    #pragma unroll
    for (int tn = 0; tn < 4; ++tn) {
        int col = n0 + wn + tn * 16 + frow;
        float badd = BIAS ? bias[col] : 0.0f;
        #pragma unroll
        for (int tm = 0; tm < 4; ++tm) {
            #pragma unroll
            for (int r = 0; r < 4; ++r) {
                size_t idx = (size_t)(m0 + wm + tm * 16 + quad * 4 + r) * 1024 + col;
                float v = acc[tm][tn][r] + badd;
                if (OF) ((float*)dst)[idx] = v;
                else    ((f16*)dst)[idx] = (f16)v;
            }
        }
    }
}

__global__ void proj_gemm(const f16* __restrict__ X, const f16* __restrict__ W,
                          const float* __restrict__ bias, f16* __restrict__ dst) {
    gemm_f16_body<false, true>(X, W, bias, dst);
}

__global__ void out_gemm(const f16* __restrict__ att, const f16* __restrict__ Wo,
                         float* __restrict__ out) {
    gemm_f16_body<true, false>(att, Wo, nullptr, out);
}

// ---------------------------------------------------------------------------
// Transpose + fp32->f16 hi/lo split: src [4][4096][1024] f32 -> dstT [4][1024][4096].
// MODE 0: dst0=hi, dst1=lo.  MODE 1: dst0=hi only.  MODE 2: dst0=lo only.
// ---------------------------------------------------------------------------
template <int MODE>
__global__ void transpose_cvt(const float* __restrict__ src, f16* __restrict__ dst0,
                              f16* __restrict__ dst1) {
    __shared__ float T[64][65];
    int n0 = blockIdx.x * 64, c0 = blockIdx.y * 64, b = blockIdx.z;
    int tid = threadIdx.x;
    const float* s = src + ((size_t)b * 4096 + n0) * 1024 + c0;
    int r = tid >> 2, q4 = tid & 3;
    #pragma unroll
    for (int i = 0; i < 4; ++i) {
        f32x4 v = *(const f32x4*)(s + (size_t)r * 1024 + q4 * 16 + i * 4);
        #pragma unroll
        for (int j = 0; j < 4; ++j) T[q4 * 16 + i * 4 + j][r] = v[j];
    }
    __syncthreads();
    int cc = tid >> 2, nq = tid & 3;
    size_t obase = ((size_t)b * 1024 + c0 + cc) * 4096 + n0 + nq * 16;
    float x[16];
    #pragma unroll
    for (int j = 0; j < 16; ++j) x[j] = T[cc][nq * 16 + j];
    f16x8 hi0, hi1;
    #pragma unroll
    for (int j = 0; j < 8; ++j) { hi0[j] = (f16)x[j]; hi1[j] = (f16)x[8 + j]; }
    if (MODE == 0 || MODE == 1) {
        *(f16x8*)(dst0 + obase) = hi0;
        *(f16x8*)(dst0 + obase + 8) = hi1;
    }
    if (MODE == 0 || MODE == 2) {
        f16x8 lo0, lo1;
        #pragma unroll
        for (int j = 0; j < 8; ++j) {
            lo0[j] = (f16)(x[j] - (float)hi0[j]);
            lo1[j] = (f16)(x[8 + j] - (float)hi1[j]);
        }
        f16* d = (MODE == 0) ? dst1 : dst0;
        *(f16x8*)(d + obase) = lo0;
        *(f16x8*)(d + obase + 8) = lo1;
    }
}

// ---------------------------------------------------------------------------
// Gram GEMM: G'[p][q] = sum_n XvT[p][n]*XkT[q][n]  (= (Xv^T Xk)[p,q] = G^T).
// K=4096 split in halves across grid.z (z = b*2 + khalf): 512 blocks (2/CU).
// NB==2: acc += A*(B0+B1) (hi*(hi+lo));  ACCUM: read-modify-write fp32 out.
// ---------------------------------------------------------------------------
template <int NB, bool ACCUM>
__global__ void gram_gemm(const f16* __restrict__ A, const f16* __restrict__ B0,
                          const f16* __restrict__ B1, float* __restrict__ G0,
                          float* __restrict__ G1) {
    __shared__ __align__(16) f16 As[128 * 64];
    __shared__ __align__(16) f16 Bs0[128 * 64];
    __shared__ __align__(16) f16 Bs1[NB == 2 ? 128 * 64 : 8];
    const int tid = threadIdx.x, lane = tid & 63, wave = tid >> 6;
    const int m0 = blockIdx.x * 128, n0 = blockIdx.y * 128;
    const int b = blockIdx.z >> 1, kh = blockIdx.z & 1;
    const int wm = (wave >> 1) * 64, wn = (wave & 1) * 64;
    const int frow = lane & 15, quad = lane >> 4;
    const f16* Ab  = A + (size_t)b * 4194304;
    const f16* B0b = B0 + (size_t)b * 4194304;
    const f16* B1b = (NB == 2) ? B1 + (size_t)b * 4194304 : nullptr;
    float* Gd = (kh ? G1 : G0) + (size_t)b * 1048576;
    const int kbase = kh * 2048;
    f32x4 acc[4][4] = {};

    for (int k0 = kbase; k0 < kbase + 2048; k0 += 64) {
        __syncthreads();
        #pragma unroll
        for (int i = 0; i < 4; ++i) {
            int slot = i * 256 + tid, row = slot >> 3, sc = slot & 7;
            int gc = sc ^ (row & 7);
            gload16(Ab + (size_t)(m0 + row) * 4096 + k0 + gc * 8, (char*)As + slot * 16);
            gload16(B0b + (size_t)(n0 + row) * 4096 + k0 + gc * 8, (char*)Bs0 + slot * 16);
            if (NB == 2)
                gload16(B1b + (size_t)(n0 + row) * 4096 + k0 + gc * 8, (char*)Bs1 + slot * 16);
        }
        __syncthreads();
        #pragma unroll
        for (int kk = 0; kk < 2; ++kk) {
            f16x8 fa[4], fb0[4], fb1[4];
            #pragma unroll
            for (int t = 0; t < 4; ++t) {
                int arow = wm + t * 16 + frow;
                int asc  = (kk * 4 + quad) ^ (arow & 7);
                fa[t] = *(const f16x8*)(As + arow * 64 + asc * 8);
                int brow = wn + t * 16 + frow;
                int bsc  = (kk * 4 + quad) ^ (brow & 7);
                fb0[t] = *(const f16x8*)(Bs0 + brow * 64 + bsc * 8);
                if (NB == 2) fb1[t] = *(const f16x8*)(Bs1 + brow * 64 + bsc * 8);
            }
            #pragma unroll
            for (int tm = 0; tm < 4; ++tm)
                #pragma unroll
                for (int tn = 0; tn < 4; ++tn) {
                    acc[tm][tn] = __builtin_amdgcn_mfma_f32_16x16x32_f16(
                        fa[tm], fb0[tn], acc[tm][tn], 0, 0, 0);
                    if (NB == 2)
                        acc[tm][tn] = __builtin_amdgcn_mfma_f32_16x16x32_f16(
                            fa[tm], fb1[tn], acc[tm][tn], 0, 0, 0);
                }
        }
    }
    #pragma unroll
    for (int tn = 0; tn < 4; ++tn) {
        int col = n0 + wn + tn * 16 + frow;
        #pragma unroll
        for (int tm = 0; tm < 4; ++tm)
            #pragma unroll
            for (int r = 0; r < 4; ++r) {
                size_t idx = (size_t)(m0 + wm + tm * 16 + quad * 4 + r) * 1024 + col;
                if (ACCUM) Gd[idx] += acc[tm][tn][r];
                else       Gd[idx]  = acc[tm][tn][r];
            }
    }
}

// ---------------------------------------------------------------------------
// A3 = Wk @ G  (A3[d][c] = sum_j Wk[d][j]*G'[c][j]), double-f16:
// terms Wkhi*Ghi + Wklo*Ghi + Wkhi*Glo. B-side stages (G0+G1) fp32 sum and
// splits hi/lo on the fly into swizzled LDS.  Output A3 stored hi/lo f16.
// grid (8,8,4).
// ---------------------------------------------------------------------------
__global__ void a3_gemm(const f16* __restrict__ wkhi, const f16* __restrict__ wklo,
                        const float* __restrict__ Gp0, const float* __restrict__ Gp1,
                        f16* __restrict__ a3hi, f16* __restrict__ a3lo) {
    __shared__ __align__(16) f16 As0[128 * 64], As1[128 * 64];
    __shared__ __align__(16) f16 Bs0[128 * 64], Bs1[128 * 64];
    const int tid = threadIdx.x, lane = tid & 63, wave = tid >> 6;
    const int m0 = blockIdx.x * 128, n0 = blockIdx.y * 128, b = blockIdx.z;
    const int wm = (wave >> 1) * 64, wn = (wave & 1) * 64;
    const int frow = lane & 15, quad = lane >> 4;
    const float* g0 = Gp0 + (size_t)b * 1048576;
    const float* g1 = Gp1 + (size_t)b * 1048576;
    f32x4 acc[4][4] = {};

    for (int k0 = 0; k0 < 1024; k0 += 64) {
        __syncthreads();
        #pragma unroll
        for (int i = 0; i < 4; ++i) {
            int slot = i * 256 + tid, row = slot >> 3, sc = slot & 7;
            int gc = sc ^ (row & 7);
            gload16(wkhi + (size_t)(m0 + row) * 1024 + k0 + gc * 8, (char*)As0 + slot * 16);
            gload16(wklo + (size_t)(m0 + row) * 1024 + k0 + gc * 8, (char*)As1 + slot * 16);
            size_t goff = (size_t)(n0 + row) * 1024 + k0 + gc * 8;
            f32x4 xa = *(const f32x4*)(g0 + goff);
            f32x4 xb = *(const f32x4*)(g0 + goff + 4);
            f32x4 ya = *(const f32x4*)(g1 + goff);
            f32x4 yb = *(const f32x4*)(g1 + goff + 4);
            f16x8 h, l;
            #pragma unroll
            for (int j = 0; j < 4; ++j) {
                float s0 = xa[j] + ya[j], s1 = xb[j] + yb[j];
                h[j] = (f16)s0;     l[j] = (f16)(s0 - (float)h[j]);
                h[4 + j] = (f16)s1; l[4 + j] = (f16)(s1 - (float)h[4 + j]);
            }
            *(f16x8*)((char*)Bs0 + slot * 16) = h;
            *(f16x8*)((char*)Bs1 + slot * 16) = l;
        }
        __syncthreads();
        #pragma unroll
        for (int kk = 0; kk < 2; ++kk) {
            f16x8 fa0[4], fa1[4], fb0[4], fb1[4];
            #pragma unroll
            for (int t = 0; t < 4; ++t) {
                int arow = wm + t * 16 + frow;
                int asc  = (kk * 4 + quad) ^ (arow & 7);
                fa0[t] = *(const f16x8*)(As0 + arow * 64 + asc * 8);
                fa1[t] = *(const f16x8*)(As1 + arow * 64 + asc * 8);
                int brow = wn + t * 16 + frow;
                int bsc  = (kk * 4 + quad) ^ (brow & 7);
                fb0[t] = *(const f16x8*)(Bs0 + brow * 64 + bsc * 8);
                fb1[t] = *(const f16x8*)(Bs1 + brow * 64 + bsc * 8);
            }
            #pragma unroll
            for (int tm = 0; tm < 4; ++tm)
                #pragma unroll
                for (int tn = 0; tn < 4; ++tn) {
                    acc[tm][tn] = __builtin_amdgcn_mfma_f32_16x16x32_f16(
                        fa0[tm], fb0[tn], acc[tm][tn], 0, 0, 0);
                    acc[tm][tn] = __builtin_amdgcn_mfma_f32_16x16x32_f16(
                        fa1[tm], fb0[tn], acc[tm][tn], 0, 0, 0);
                    acc[tm][tn] = __builtin_amdgcn_mfma_f32_16x16x32_f16(
                        fa0[tm], fb1[tn], acc[tm][tn], 0, 0, 0);
                }
        }
    }
    #pragma unroll
    for (int tn = 0; tn < 4; ++tn) {
        int col = n0 + wn + tn * 16 + frow;
        #pragma unroll
        for (int tm = 0; tm < 4; ++tm)
            #pragma unroll
            for (int r = 0; r < 4; ++r) {
                size_t idx = (size_t)b * 1048576 +
                             (size_t)(m0 + wm + tm * 16 + quad * 4 + r) * 1024 + col;
                float v = acc[tm][tn][r];
                f16 h = (f16)v;
                a3hi[idx] = h;
                a3lo[idx] = (f16)(v - (float)h);
            }
    }
}

// ---------------------------------------------------------------------------
// Rank-1 bias helpers: column sums of fp32 k,v then u=Wk@sk, w=Wv@sv (fp32).
// ---------------------------------------------------------------------------
__global__ void colsum_part(const float* __restrict__ k, const float* __restrict__ v,
                            float* __restrict__ pk, float* __restrict__ pv) {
    const float* src = blockIdx.z ? v : k;
    float* dst = blockIdx.z ? pv : pk;
    int nc = blockIdx.x, b = blockIdx.y, tid = threadIdx.x;
    const float* p = src + (size_t)b * 4194304 + (size_t)nc * 65536;
    float s[4] = {0.f, 0.f, 0.f, 0.f};
    for (int n = 0; n < 64; ++n) {
        #pragma unroll
        for (int j = 0; j < 4; ++j) s[j] += p[(size_t)n * 1024 + tid + j * 256];
    }
    #pragma unroll
    for (int j = 0; j < 4; ++j)
        dst[(size_t)nc * 4096 + b * 1024 + tid + j * 256] = s[j];
}

__global__ void colsum_reduce(const float* __restrict__ pk, const float* __restrict__ pv,
                              float* __restrict__ sk, float* __restrict__ sv) {
    int i = blockIdx.x * 256 + threadIdx.x;      // 0..8191
    const float* p = (i >= 4096) ? pv : pk;
    float* dst = (i >= 4096) ? sv : sk;
    int j = i & 4095;
    float s = 0.f;
    #pragma unroll
    for (int t = 0; t < 64; ++t) s += p[(size_t)t * 4096 + j];
    dst[j] = s;
}

__global__ void bias_vec(const float* __restrict__ sk, const float* __restrict__ sv,
                         const float* __restrict__ Wk, const float* __restrict__ Wv,
                         float* __restrict__ u, float* __restrict__ w) {
    int gid = blockIdx.x * 4 + (threadIdx.x >> 6);   // 0..4095
    int lane = threadIdx.x & 63;
    int b = gid >> 10, d = gid & 1023;
    const float* W = blockIdx.y ? Wv : Wk;
    const float* s = blockIdx.y ? sv : sk;
    float* dst = blockIdx.y ? w : u;
    const float* wr = W + (size_t)d * 1024;
    const float* sr = s + b * 1024;
    float acc = 0.f;
    #pragma unroll
    for (int t = 0; t < 16; ++t) acc += wr[lane + t * 64] * sr[lane + t * 64];
    #pragma unroll
    for (int s2 = 32; s2; s2 >>= 1) acc += __shfl_xor(acc, s2, 64);
    if (lane == 0) dst[b * 1024 + d] = acc;
}

// ---------------------------------------------------------------------------
// ctx per head: ctx[dd][ee] = sum_k A3[h64+dd][k]*Wv[h64+ee][k] (double-f16)
//   + bk[d]*w[e] + bv[e]*u[d] + 4096*bk[d]*bv[e];  softmax over dd; *INV_QTR;
// store ctxT[bh][ee][dd] f16.  grid (64).
// ---------------------------------------------------------------------------
__global__ void ctx_gemm_softmax(const f16* __restrict__ a3hi, const f16* __restrict__ a3lo,
                                 const f16* __restrict__ wvhi, const f16* __restrict__ wvlo,
                                 const float* __restrict__ u, const float* __restrict__ wvec,
                                 const float* __restrict__ bk, const float* __restrict__ bv,
                                 f16* __restrict__ ctxT) {
    __shared__ __align__(16) f16 As0[64 * 64], As1[64 * 64], Bs0[64 * 64], Bs1[64 * 64];
    __shared__ float cs[64 * 65];
    int bh = blockIdx.x, b = bh >> 4, h = bh & 15;
    int tid = threadIdx.x, lane = tid & 63, wave = tid >> 6;
    const size_t abase = (size_t)b * 1048576 + (size_t)(h * 64) * 1024;
    const size_t wbase = (size_t)(h * 64) * 1024;
    int frow = lane & 15, quad = lane >> 4;
    f32x4 acc[4] = {};

    for (int k0 = 0; k0 < 1024; k0 += 64) {
        __syncthreads();
        #pragma unroll
        for (int i = 0; i < 2; ++i) {
            int slot = i * 256 + tid, row = slot >> 3, sc = slot & 7;
            int gc = sc ^ (row & 7);
            size_t ro = (size_t)row * 1024 + k0 + gc * 8;
            gload16(a3hi + abase + ro, (char*)As0 + slot * 16);
            gload16(a3lo + abase + ro, (char*)As1 + slot * 16);
            gload16(wvhi + wbase + ro, (char*)Bs0 + slot * 16);
            gload16(wvlo + wbase + ro, (char*)Bs1 + slot * 16);
        }
        __syncthreads();
        #pragma unroll
        for (int kk = 0; kk < 2; ++kk) {
            int arow = wave * 16 + frow;
            int asc  = (kk * 4 + quad) ^ (arow & 7);
            f16x8 fa0 = *(const f16x8*)(As0 + arow * 64 + asc * 8);
            f16x8 fa1 = *(const f16x8*)(As1 + arow * 64 + asc * 8);
            #pragma unroll
            for (int tn = 0; tn < 4; ++tn) {
                int brow = tn * 16 + frow;
                int bsc  = (kk * 4 + quad) ^ (brow & 7);
                f16x8 fb0 = *(const f16x8*)(Bs0 + brow * 64 + bsc * 8);
                f16x8 fb1 = *(const f16x8*)(Bs1 + brow * 64 + bsc * 8);
                acc[tn] = __builtin_amdgcn_mfma_f32_16x16x32_f16(fa0, fb0, acc[tn], 0, 0, 0);
                acc[tn] = __builtin_amdgcn_mfma_f32_16x16x32_f16(fa1, fb0, acc[tn], 0, 0, 0);
                acc[tn] = __builtin_amdgcn_mfma_f32_16x16x32_f16(fa0, fb1, acc[tn], 0, 0, 0);
            }
        }
    }

    const float* ub  = u + b * 1024 + h * 64;
    const float* wb  = wvec + b * 1024 + h * 64;
    const float* bkh = bk + h * 64;
    const float* bvh = bv + h * 64;
    #pragma unroll
    for (int tn = 0; tn < 4; ++tn) {
        int ee = tn * 16 + frow;
        float bve = bvh[ee], we = wb[ee];
        #pragma unroll
        for (int r = 0; r < 4; ++r) {
            int dd = wave * 16 + quad * 4 + r;
            float bkd = bkh[dd], ud = ub[dd];
            cs[dd * 65 + ee] = acc[tn][r] + bkd * we + bve * ud + 4096.0f * bkd * bve;
        }
    }
    __syncthreads();
    #pragma unroll
    for (int i = 0; i < 16; ++i) {
        int e = wave * 16 + i;
        float x = cs[lane * 65 + e];
        float m = x;
        #pragma unroll
        for (int s2 = 32; s2; s2 >>= 1) m = fmaxf(m, __shfl_xor(m, s2, 64));
        float ex = __expf(x - m);
        float sum = ex;
        #pragma unroll
        for (int s2 = 32; s2; s2 >>= 1) sum += __shfl_xor(sum, s2, 64);
        ctxT[((size_t)bh * 64 + e) * 64 + lane] = (f16)(ex / sum * INV_QTR);
    }
}

// ---------------------------------------------------------------------------
// qs = softmax(qp over 64-wide head group) * INV_QTR, in place (f16 buffer).
// ---------------------------------------------------------------------------
__global__ void q_softmax(f16* __restrict__ qp) {
    int gid  = blockIdx.x * 4 + (threadIdx.x >> 6);
    int lane = threadIdx.x & 63;
    size_t off = (size_t)gid * 64 + lane;
    float x = (float)qp[off];
    float m = x;
    #pragma unroll
    for (int s = 32; s; s >>= 1) m = fmaxf(m, __shfl_xor(m, s, 64));
    float e = __expf(x - m);
    float sum = e;
    #pragma unroll
    for (int s = 32; s; s >>= 1) sum += __shfl_xor(sum, s, 64);
    qp[off] = (f16)(e / sum * INV_QTR);
}

// ---------------------------------------------------------------------------
// att = qs @ ctx per head (block-diagonal, K=64). grid (128, 8). All f16.
// ---------------------------------------------------------------------------
__global__ void att_gemm(const f16* __restrict__ qs, const f16* __restrict__ ctxT,
                         f16* __restrict__ att) {
    __shared__ __align__(16) f16 As[2][128 * 64];
    __shared__ __align__(16) f16 Bs[2][64 * 64];
    int tid = threadIdx.x, lane = tid & 63, wave = tid >> 6;
    int m0 = blockIdx.x * 128;
    int n0 = blockIdx.y * 128;
    int b  = m0 >> 12;
    int h0 = (n0 >> 6) & 15;

    #pragma unroll
    for (int ch = 0; ch < 2; ++ch) {
        #pragma unroll
        for (int i = 0; i < 4; ++i) {
            int slot = i * 256 + tid, row = slot >> 3, sc = slot & 7, gc = sc ^ (row & 7);
            gload16(qs + (size_t)(m0 + row) * 1024 + n0 + ch * 64 + gc * 8,
                    (char*)As[ch] + slot * 16);
        }
        #pragma unroll
        for (int i = 0; i < 2; ++i) {
            int slot = i * 256 + tid, row = slot >> 3, sc = slot & 7, gc = sc ^ (row & 7);
            int bh = b * 16 + h0 + ch;
            gload16(ctxT + ((size_t)bh * 64 + row) * 64 + gc * 8,
                    (char*)Bs[ch] + slot * 16);
        }
    }
    __syncthreads();

    int wm = (wave >> 1) * 64, wn = wave & 1;
    int frow = lane & 15, quad = lane >> 4;
    f32x4 acc[4][4] = {};
    #pragma unroll
    for (int kk = 0; kk < 2; ++kk) {
        f16x8 fa[4], fb[4];
        #pragma unroll
        for (int t = 0; t < 4; ++t) {
            int arow = wm + t * 16 + frow;
            int asc  = (kk * 4 + quad) ^ (arow & 7);
            fa[t] = *(const f16x8*)(As[wn] + arow * 64 + asc * 8);
            int brow = t * 16 + frow;
            int bsc  = (kk * 4 + quad) ^ (brow & 7);
            fb[t] = *(const f16x8*)(Bs[wn] + brow * 64 + bsc * 8);
        }
        #pragma unroll
        for (int tm = 0; tm < 4; ++tm)
            #pragma unroll
            for (int tn = 0; tn < 4; ++tn)
                acc[tm][tn] = __builtin_amdgcn_mfma_f32_16x16x32_f16(
                    fa[tm], fb[tn], acc[tm][tn], 0, 0, 0);
    }
    #pragma unroll
    for (int tn = 0; tn < 4; ++tn) {
        int col = n0 + wn * 64 + tn * 16 + frow;
        #pragma unroll
        for (int tm = 0; tm < 4; ++tm) {
            #pragma unroll
            for (int r = 0; r < 4; ++r) {
                int row = m0 + wm + tm * 16 + quad * 4 + r;
                att[(size_t)row * 1024 + col] = (f16)acc[tm][tn][r];
            }
        }
    }
}

// ---------------------------------------------------------------------------
// cvt kernels
// ---------------------------------------------------------------------------
__device__ __forceinline__ void cvt8_hilo(const float* src, f16* dh, f16* dl, bool lo) {
    f32x4 a = ((const f32x4*)src)[0];
    f32x4 b = ((const f32x4*)src)[1];
    f16x8 h, l;
    #pragma unroll
    for (int j = 0; j < 4; ++j) {
        h[j] = (f16)a[j];     h[j + 4] = (f16)b[j];
        l[j] = (f16)(a[j] - (float)h[j]);
        l[j + 4] = (f16)(b[j] - (float)h[j + 4]);
    }
    *(f16x8*)dh = h;
    if (lo) *(f16x8*)dl = l;
}

// Wk, Wv -> hi + lo f16.  grid (512, 2).
__global__ void cvt_w_kv(const float* __restrict__ Wk, const float* __restrict__ Wv,
                         f16* __restrict__ whik, f16* __restrict__ whiv,
                         f16* __restrict__ wlok, f16* __restrict__ wlov) {
    const float* s = blockIdx.y ? Wv : Wk;
    f16* dh = blockIdx.y ? whiv : whik;
    f16* dl = blockIdx.y ? wlov : wlok;
    size_t i = ((size_t)blockIdx.x * 256 + threadIdx.x) * 8;
    cvt8_hilo(s + i, dh + i, dl + i, true);
}

// q -> f16; Wq, Wo -> hi f16.  grid (9216).
__global__ void cvt_q_wqo(const float* __restrict__ q, const float* __restrict__ Wq,
                          const float* __restrict__ Wo, f16* __restrict__ qh,
                          f16* __restrict__ wqhi, f16* __restrict__ wohi) {
    size_t i = ((size_t)blockIdx.x * 256 + threadIdx.x) * 8;
    const float* src;
    f16* dst;
    if (i < 16777216) { src = q + i; dst = qh + i; }
    else {
        size_t wi = i - 16777216;
        if (wi < 1048576) { src = Wq + wi; dst = wqhi + wi; }
        else              { src = Wo + (wi - 1048576); dst = wohi + (wi - 1048576); }
    }
    cvt8_hilo(src, dst, nullptr, false);
}

// ---------------------------------------------------------------------------
// Buffer plan (Mi = 1<<20 bytes; ws peak = 72Mi, same as known-good footprint):
// d_out (64Mi): [XkT_hi 0-32 | XkT_lo->XvT_lo 32-64] -> [qh 0-32 | qp 32-64]
//               -> final fp32 out (0-64).
// ws:  0-8   A3hi (after XvT_hi dead)      32-48  G0 fp32
//      8-16  A3lo                          48-64  G1 fp32
//      16Mi  ctxT (512Ki); 17Mi u,w,sk,sv; 18Mi pk; 19Mi pv;
//      20Mi  Wqhi (2Mi); 22Mi Wohi (2Mi);  24-56  att (after G dead)
//      64Mi Wkhi | 66Mi Wvhi | 68Mi Wklo | 70Mi Wvlo   (end 72Mi)
// ---------------------------------------------------------------------------
extern "C" void kernel_launch(void* const* d_in, const int* in_sizes, int n_in,
                              void* d_out, int out_size, void* d_ws, size_t ws_size,
                              hipStream_t stream) {
    const float* q  = (const float*)d_in[0];
    const float* k  = (const float*)d_in[1];
    const float* v  = (const float*)d_in[2];
    const float* Wq = (const float*)d_in[3];
    const float* bq = (const float*)d_in[4];
    const float* Wk = (const float*)d_in[5];
    const float* bk = (const float*)d_in[6];
    const float* Wv = (const float*)d_in[7];
    const float* bv = (const float*)d_in[8];
    const float* Wo = (const float*)d_in[9];

    const size_t Mi = 1048576;
    char* ws = (char*)d_ws;
    char* ob = (char*)d_out;

    f16*   A3hi = (f16*)ws;
    f16*   A3lo = (f16*)(ws + 8 * Mi);
    f16*   ctxT = (f16*)(ws + 16 * Mi);
    float* u    = (float*)(ws + 17 * Mi);
    float* w    = (float*)(ws + 17 * Mi + 65536);
    float* sk   = (float*)(ws + 17 * Mi + 131072);
    float* sv   = (float*)(ws + 17 * Mi + 196608);
    float* pk   = (float*)(ws + 18 * Mi);
    float* pv   = (float*)(ws + 19 * Mi);
    f16*   Wqhi = (f16*)(ws + 20 * Mi);
    f16*   Wohi = (f16*)(ws + 22 * Mi);
    f16*   att  = (f16*)(ws + 24 * Mi);
    float* G0   = (float*)(ws + 32 * Mi);
    float* G1   = (float*)(ws + 48 * Mi);
    f16*   XvTh = (f16*)ws;                      // 0-32Mi, dead before A3 written
    f16*   Wkhi = (f16*)(ws + 64 * Mi);
    f16*   Wvhi = (f16*)(ws + 66 * Mi);
    f16*   Wklo = (f16*)(ws + 68 * Mi);
    f16*   Wvlo = (f16*)(ws + 70 * Mi);

    f16*   XkTh = (f16*)ob;                      // d_out 0-32Mi
    f16*   XkTl = (f16*)(ob + 32 * Mi);          // then XvT_lo, then qp
    f16*   XvTl = (f16*)(ob + 32 * Mi);
    f16*   qh   = (f16*)ob;
    f16*   qp   = (f16*)(ob + 32 * Mi);
    float* out  = (float*)d_out;

    // weights hi/lo for the high-precision ctx path
    cvt_w_kv<<<dim3(512, 2), 256, 0, stream>>>(Wk, Wv, Wkhi, Wvhi, Wklo, Wvlo);
    // transposed hi/lo inputs
    transpose_cvt<0><<<dim3(64, 16, 4), 256, 0, stream>>>(k, XkTh, XkTl);
    transpose_cvt<1><<<dim3(64, 16, 4), 256, 0, stream>>>(v, XvTh, nullptr);
    // G' = Xv^T Xk, double-f16: hi*(hi+lo) then + lo*hi
    gram_gemm<2, false><<<dim3(8, 8, 8), 256, 0, stream>>>(XvTh, XkTh, XkTl, G0, G1);
    transpose_cvt<2><<<dim3(64, 16, 4), 256, 0, stream>>>(v, XvTl, nullptr);
    gram_gemm<1, true><<<dim3(8, 8, 8), 256, 0, stream>>>(XvTl, XkTh, nullptr, G0, G1);
    // A3 = Wk @ G (fp32 partials summed + split in staging)
    a3_gemm<<<dim3(8, 8, 4), 256, 0, stream>>>(Wkhi, Wklo, G0, G1, A3hi, A3lo);
    // rank-1 bias terms (exact fp32)
    colsum_part<<<dim3(64, 4, 2), 256, 0, stream>>>(k, v, pk, pv);
    colsum_reduce<<<32, 256, 0, stream>>>(pk, pv, sk, sv);
    bias_vec<<<dim3(1024, 2), 256, 0, stream>>>(sk, sv, Wk, Wv, u, w);
    // ctx + softmax -> ctxT
    ctx_gemm_softmax<<<64, 256, 0, stream>>>(A3hi, A3lo, Wvhi, Wvlo, u, w, bk, bv, ctxT);
    // Q path (f16 is sufficient here: feature softmax bounds sensitivity)
    cvt_q_wqo<<<9216, 256, 0, stream>>>(q, Wq, Wo, qh, Wqhi, Wohi);
    proj_gemm<<<dim3(128, 8), 256, 0, stream>>>(qh, Wqhi, bq, qp);
    q_softmax<<<65536, 256, 0, stream>>>(qp);
    att_gemm<<<dim3(128, 8), 256, 0, stream>>>(qp, ctxT, att);
    out_gemm<<<dim3(128, 8), 256, 0, stream>>>(att, Wohi, out);
}

// Round 4
// 633.615 us; speedup vs baseline: 1.1948x; 1.1948x over previous
//
#include <hip/hip_runtime.h>

#define INV_QTR 0.59460355750136053f   // 8^(-1/4)

typedef _Float16 f16;
typedef _Float16 f16x8 __attribute__((ext_vector_type(8)));
typedef float f32x4 __attribute__((ext_vector_type(4)));

__device__ __forceinline__ void gload16(const void* g, void* l) {
    __builtin_amdgcn_global_load_lds(
        (const __attribute__((address_space(1))) void*)g,
        (__attribute__((address_space(3))) void*)l, 16, 0, 0);
}

// ---------------------------------------------------------------------------
// All-f16 BT-GEMM (m97 structure): dst[m][n] = sum_k X[m][k]*W[n][k] (+bias).
// 128x128 tile, BK=64, global_load_lds width=16, XOR swizzle on 16B chunks,
// 16x16x32 f16 MFMA, fp32 accum.
// QSM: fused feature-softmax over the 64-wide head group + *INV_QTR (Q path).
// ---------------------------------------------------------------------------
template <bool OF, bool BIAS, bool QSM>
__device__ __forceinline__ void gemm_f16_body(const f16* __restrict__ X,
                                              const f16* __restrict__ W,
                                              const float* __restrict__ bias,
                                              void* __restrict__ dst) {
    __shared__ __align__(16) f16 As[128 * 64];
    __shared__ __align__(16) f16 Bs[128 * 64];

    const int tid  = threadIdx.x;
    const int lane = tid & 63;
    const int wave = tid >> 6;
    const int m0   = blockIdx.x * 128;
    const int n0   = blockIdx.y * 128;
    const int wm   = (wave >> 1) * 64;
    const int wn   = (wave & 1) * 64;
    const int frow = lane & 15;
    const int quad = lane >> 4;

    f32x4 acc[4][4] = {};

    for (int k0 = 0; k0 < 1024; k0 += 64) {
        __syncthreads();
        #pragma unroll
        for (int i = 0; i < 4; ++i) {
            int slot = i * 256 + tid;
            int row  = slot >> 3;
            int sc   = slot & 7;
            int gc   = sc ^ (row & 7);
            gload16(X + (size_t)(m0 + row) * 1024 + k0 + gc * 8,
                    (char*)As + slot * 16);
            gload16(W + (size_t)(n0 + row) * 1024 + k0 + gc * 8,
                    (char*)Bs + slot * 16);
        }
        __syncthreads();

        #pragma unroll
        for (int kk = 0; kk < 2; ++kk) {
            f16x8 fa[4], fb[4];
            #pragma unroll
            for (int t = 0; t < 4; ++t) {
                int arow = wm + t * 16 + frow;
                int asc  = (kk * 4 + quad) ^ (arow & 7);
                fa[t] = *(const f16x8*)(As + arow * 64 + asc * 8);
                int brow = wn + t * 16 + frow;
                int bsc  = (kk * 4 + quad) ^ (brow & 7);
                fb[t] = *(const f16x8*)(Bs + brow * 64 + bsc * 8);
            }
            #pragma unroll
            for (int tm = 0; tm < 4; ++tm)
                #pragma unroll
                for (int tn = 0; tn < 4; ++tn)
                    acc[tm][tn] = __builtin_amdgcn_mfma_f32_16x16x32_f16(
                        fa[tm], fb[tn], acc[tm][tn], 0, 0, 0);
        }
    }

    if (QSM) {
        // Each row's 64 head values: tn regs x 16 frow lanes (within quad).
        float badd[4];
        #pragma unroll
        for (int tn = 0; tn < 4; ++tn) badd[tn] = bias[n0 + wn + tn * 16 + frow];
        #pragma unroll
        for (int tm = 0; tm < 4; ++tm) {
            #pragma unroll
            for (int r = 0; r < 4; ++r) {
                float x[4], m = -1e30f;
                #pragma unroll
                for (int tn = 0; tn < 4; ++tn) {
                    x[tn] = acc[tm][tn][r] + badd[tn];
                    m = fmaxf(m, x[tn]);
                }
                #pragma unroll
                for (int s = 1; s < 16; s <<= 1) m = fmaxf(m, __shfl_xor(m, s, 64));
                float e[4], sum = 0.f;
                #pragma unroll
                for (int tn = 0; tn < 4; ++tn) { e[tn] = __expf(x[tn] - m); sum += e[tn]; }
                #pragma unroll
                for (int s = 1; s < 16; s <<= 1) sum += __shfl_xor(sum, s, 64);
                float inv = INV_QTR / sum;
                size_t rowb = (size_t)(m0 + wm + tm * 16 + quad * 4 + r) * 1024;
                #pragma unroll
                for (int tn = 0; tn < 4; ++tn)
                    ((f16*)dst)[rowb + n0 + wn + tn * 16 + frow] = (f16)(e[tn] * inv);
            }
        }
        return;
    }

    #pragma unroll
    for (int tn = 0; tn < 4; ++tn) {
        int col = n0 + wn + tn * 16 + frow;
        float badd = BIAS ? bias[col] : 0.0f;
        #pragma unroll
        for (int tm = 0; tm < 4; ++tm) {
            #pragma unroll
            for (int r = 0; r < 4; ++r) {
                size_t idx = (size_t)(m0 + wm + tm * 16 + quad * 4 + r) * 1024 + col;
                float v = acc[tm][tn][r] + badd;
                if (OF) ((float*)dst)[idx] = v;
                else    ((f16*)dst)[idx] = (f16)v;
            }
        }
    }
}

// Q projection with fused feature-softmax.  grid (128, 8).
__global__ void proj_qsm_gemm(const f16* __restrict__ X, const f16* __restrict__ W,
                              const float* __restrict__ bias, f16* __restrict__ dst) {
    gemm_f16_body<false, true, true>(X, W, bias, dst);
}

// out = att @ Wo^T (no bias), fp32 out.  grid (128, 8).
__global__ void out_gemm(const f16* __restrict__ att, const f16* __restrict__ Wo,
                         float* __restrict__ out) {
    gemm_f16_body<true, false, false>(att, Wo, nullptr, out);
}

// ---------------------------------------------------------------------------
// Transpose + fp32->f16 hi/lo split: src [4][4096][1024] f32 -> dstT [4][1024][4096].
// MODE 0: dst0=hi, dst1=lo.  MODE 1: dst0=hi only.  MODE 2: dst0=lo only.
// CS: fold column-sum (over n) into csum[b*1024+c] via one atomicAdd/block/col.
// ---------------------------------------------------------------------------
template <int MODE, bool CS>
__global__ void transpose_cvt(const float* __restrict__ src, f16* __restrict__ dst0,
                              f16* __restrict__ dst1, float* __restrict__ csum) {
    __shared__ float T[64][65];
    int n0 = blockIdx.x * 64, c0 = blockIdx.y * 64, b = blockIdx.z;
    int tid = threadIdx.x;
    const float* s = src + ((size_t)b * 4096 + n0) * 1024 + c0;
    int r = tid >> 2, q4 = tid & 3;
    #pragma unroll
    for (int i = 0; i < 4; ++i) {
        f32x4 v = *(const f32x4*)(s + (size_t)r * 1024 + q4 * 16 + i * 4);
        #pragma unroll
        for (int j = 0; j < 4; ++j) T[q4 * 16 + i * 4 + j][r] = v[j];
    }
    __syncthreads();
    int cc = tid >> 2, nq = tid & 3;
    size_t obase = ((size_t)b * 1024 + c0 + cc) * 4096 + n0 + nq * 16;
    float x[16];
    #pragma unroll
    for (int j = 0; j < 16; ++j) x[j] = T[cc][nq * 16 + j];
    if (CS) {
        float ssum = 0.f;
        #pragma unroll
        for (int j = 0; j < 16; ++j) ssum += x[j];
        ssum += __shfl_xor(ssum, 1, 64);
        ssum += __shfl_xor(ssum, 2, 64);
        if (nq == 0) atomicAdd(csum + b * 1024 + c0 + cc, ssum);
    }
    f16x8 hi0, hi1;
    #pragma unroll
    for (int j = 0; j < 8; ++j) { hi0[j] = (f16)x[j]; hi1[j] = (f16)x[8 + j]; }
    if (MODE == 0 || MODE == 1) {
        *(f16x8*)(dst0 + obase) = hi0;
        *(f16x8*)(dst0 + obase + 8) = hi1;
    }
    if (MODE == 0 || MODE == 2) {
        f16x8 lo0, lo1;
        #pragma unroll
        for (int j = 0; j < 8; ++j) {
            lo0[j] = (f16)(x[j] - (float)hi0[j]);
            lo1[j] = (f16)(x[8 + j] - (float)hi1[j]);
        }
        f16* d = (MODE == 0) ? dst1 : dst0;
        *(f16x8*)(d + obase) = lo0;
        *(f16x8*)(d + obase + 8) = lo1;
    }
}

// ---------------------------------------------------------------------------
// Gram GEMM: G'[p][q] = sum_n XvT[p][n]*XkT[q][n]  (= (Xv^T Xk)[p,q] = G^T).
// K=4096 split in halves across grid.z (z = b*2 + khalf): 512 blocks (2/CU).
// NB==2: acc += A*(B0+B1) (hi*(hi+lo));  ACCUM: read-modify-write fp32 out.
// ---------------------------------------------------------------------------
template <int NB, bool ACCUM>
__global__ void gram_gemm(const f16* __restrict__ A, const f16* __restrict__ B0,
                          const f16* __restrict__ B1, float* __restrict__ G0,
                          float* __restrict__ G1) {
    __shared__ __align__(16) f16 As[128 * 64];
    __shared__ __align__(16) f16 Bs0[128 * 64];
    __shared__ __align__(16) f16 Bs1[NB == 2 ? 128 * 64 : 8];
    const int tid = threadIdx.x, lane = tid & 63, wave = tid >> 6;
    const int m0 = blockIdx.x * 128, n0 = blockIdx.y * 128;
    const int b = blockIdx.z >> 1, kh = blockIdx.z & 1;
    const int wm = (wave >> 1) * 64, wn = (wave & 1) * 64;
    const int frow = lane & 15, quad = lane >> 4;
    const f16* Ab  = A + (size_t)b * 4194304;
    const f16* B0b = B0 + (size_t)b * 4194304;
    const f16* B1b = (NB == 2) ? B1 + (size_t)b * 4194304 : nullptr;
    float* Gd = (kh ? G1 : G0) + (size_t)b * 1048576;
    const int kbase = kh * 2048;
    f32x4 acc[4][4] = {};

    for (int k0 = kbase; k0 < kbase + 2048; k0 += 64) {
        __syncthreads();
        #pragma unroll
        for (int i = 0; i < 4; ++i) {
            int slot = i * 256 + tid, row = slot >> 3, sc = slot & 7;
            int gc = sc ^ (row & 7);
            gload16(Ab + (size_t)(m0 + row) * 4096 + k0 + gc * 8, (char*)As + slot * 16);
            gload16(B0b + (size_t)(n0 + row) * 4096 + k0 + gc * 8, (char*)Bs0 + slot * 16);
            if (NB == 2)
                gload16(B1b + (size_t)(n0 + row) * 4096 + k0 + gc * 8, (char*)Bs1 + slot * 16);
        }
        __syncthreads();
        #pragma unroll
        for (int kk = 0; kk < 2; ++kk) {
            f16x8 fa[4], fb0[4], fb1[4];
            #pragma unroll
            for (int t = 0; t < 4; ++t) {
                int arow = wm + t * 16 + frow;
                int asc  = (kk * 4 + quad) ^ (arow & 7);
                fa[t] = *(const f16x8*)(As + arow * 64 + asc * 8);
                int brow = wn + t * 16 + frow;
                int bsc  = (kk * 4 + quad) ^ (brow & 7);
                fb0[t] = *(const f16x8*)(Bs0 + brow * 64 + bsc * 8);
                if (NB == 2) fb1[t] = *(const f16x8*)(Bs1 + brow * 64 + bsc * 8);
            }
            #pragma unroll
            for (int tm = 0; tm < 4; ++tm)
                #pragma unroll
                for (int tn = 0; tn < 4; ++tn) {
                    acc[tm][tn] = __builtin_amdgcn_mfma_f32_16x16x32_f16(
                        fa[tm], fb0[tn], acc[tm][tn], 0, 0, 0);
                    if (NB == 2)
                        acc[tm][tn] = __builtin_amdgcn_mfma_f32_16x16x32_f16(
                            fa[tm], fb1[tn], acc[tm][tn], 0, 0, 0);
                }
        }
    }
    #pragma unroll
    for (int tn = 0; tn < 4; ++tn) {
        int col = n0 + wn + tn * 16 + frow;
        #pragma unroll
        for (int tm = 0; tm < 4; ++tm)
            #pragma unroll
            for (int r = 0; r < 4; ++r) {
                size_t idx = (size_t)(m0 + wm + tm * 16 + quad * 4 + r) * 1024 + col;
                if (ACCUM) Gd[idx] += acc[tm][tn][r];
                else       Gd[idx]  = acc[tm][tn][r];
            }
    }
}

// ---------------------------------------------------------------------------
// combine_split: hi/lo f16 split of (a[i]+b[i]).  8 elems/thread.
// Used for G0+G1 -> Ghi/Glo and P0+P1 -> A3hi/A3lo (coalesced f16x8 stores).
// ---------------------------------------------------------------------------
__global__ void combine_split(const float* __restrict__ a, const float* __restrict__ b,
                              f16* __restrict__ hi, f16* __restrict__ lo) {
    size_t i = ((size_t)blockIdx.x * 256 + threadIdx.x) * 8;
    f32x4 a0 = *(const f32x4*)(a + i);
    f32x4 a1 = *(const f32x4*)(a + i + 4);
    f32x4 b0 = *(const f32x4*)(b + i);
    f32x4 b1 = *(const f32x4*)(b + i + 4);
    f16x8 h, l;
    #pragma unroll
    for (int j = 0; j < 4; ++j) {
        float s0 = a0[j] + b0[j], s1 = a1[j] + b1[j];
        h[j] = (f16)s0;     l[j] = (f16)(s0 - (float)h[j]);
        h[4 + j] = (f16)s1; l[4 + j] = (f16)(s1 - (float)h[4 + j]);
    }
    *(f16x8*)(hi + i) = h;
    *(f16x8*)(lo + i) = l;
}

// ---------------------------------------------------------------------------
// a3 = Wk @ G' (3-term double-f16, all panels via global_load_lds).
// K=1024 split across kh: grid (8,8,8), z = b*2+kh -> 512 blocks (2/CU).
// Writes fp32 partials P0 (kh=0) / P1 (kh=1); no RMW.
// ---------------------------------------------------------------------------
__global__ void a3f16_gemm(const f16* __restrict__ wkhi, const f16* __restrict__ wklo,
                           const f16* __restrict__ ghi, const f16* __restrict__ glo,
                           float* __restrict__ P0, float* __restrict__ P1) {
    __shared__ __align__(16) f16 As0[128 * 64], As1[128 * 64];
    __shared__ __align__(16) f16 Bs0[128 * 64], Bs1[128 * 64];
    const int tid = threadIdx.x, lane = tid & 63, wave = tid >> 6;
    const int m0 = blockIdx.x * 128, n0 = blockIdx.y * 128;
    const int b = blockIdx.z >> 1, kh = blockIdx.z & 1;
    const int wm = (wave >> 1) * 64, wn = (wave & 1) * 64;
    const int frow = lane & 15, quad = lane >> 4;
    const f16* g0b = ghi + (size_t)b * 1048576;
    const f16* g1b = glo + (size_t)b * 1048576;
    float* Pd = (kh ? P1 : P0) + (size_t)b * 1048576;
    const int kbase = kh * 512;
    f32x4 acc[4][4] = {};

    for (int k0 = kbase; k0 < kbase + 512; k0 += 64) {
        __syncthreads();
        #pragma unroll
        for (int i = 0; i < 4; ++i) {
            int slot = i * 256 + tid, row = slot >> 3, sc = slot & 7;
            int gc = sc ^ (row & 7);
            size_t ao = (size_t)(m0 + row) * 1024 + k0 + gc * 8;
            size_t bo = (size_t)(n0 + row) * 1024 + k0 + gc * 8;
            gload16(wkhi + ao, (char*)As0 + slot * 16);
            gload16(wklo + ao, (char*)As1 + slot * 16);
            gload16(g0b + bo, (char*)Bs0 + slot * 16);
            gload16(g1b + bo, (char*)Bs1 + slot * 16);
        }
        __syncthreads();
        #pragma unroll
        for (int kk = 0; kk < 2; ++kk) {
            f16x8 fa0[4], fa1[4], fb0[4], fb1[4];
            #pragma unroll
            for (int t = 0; t < 4; ++t) {
                int arow = wm + t * 16 + frow;
                int asc  = (kk * 4 + quad) ^ (arow & 7);
                fa0[t] = *(const f16x8*)(As0 + arow * 64 + asc * 8);
                fa1[t] = *(const f16x8*)(As1 + arow * 64 + asc * 8);
                int brow = wn + t * 16 + frow;
                int bsc  = (kk * 4 + quad) ^ (brow & 7);
                fb0[t] = *(const f16x8*)(Bs0 + brow * 64 + bsc * 8);
                fb1[t] = *(const f16x8*)(Bs1 + brow * 64 + bsc * 8);
            }
            #pragma unroll
            for (int tm = 0; tm < 4; ++tm)
                #pragma unroll
                for (int tn = 0; tn < 4; ++tn) {
                    acc[tm][tn] = __builtin_amdgcn_mfma_f32_16x16x32_f16(
                        fa0[tm], fb0[tn], acc[tm][tn], 0, 0, 0);
                    acc[tm][tn] = __builtin_amdgcn_mfma_f32_16x16x32_f16(
                        fa1[tm], fb0[tn], acc[tm][tn], 0, 0, 0);
                    acc[tm][tn] = __builtin_amdgcn_mfma_f32_16x16x32_f16(
                        fa0[tm], fb1[tn], acc[tm][tn], 0, 0, 0);
                }
        }
    }
    #pragma unroll
    for (int tn = 0; tn < 4; ++tn) {
        int col = n0 + wn + tn * 16 + frow;
        #pragma unroll
        for (int tm = 0; tm < 4; ++tm)
            #pragma unroll
            for (int r = 0; r < 4; ++r)
                Pd[(size_t)(m0 + wm + tm * 16 + quad * 4 + r) * 1024 + col] =
                    acc[tm][tn][r];
    }
}

// ---------------------------------------------------------------------------
// zero 8192 floats (sk|sv) for the atomic column sums.  grid (8).
// ---------------------------------------------------------------------------
__global__ void zero_f32(float* __restrict__ p) {
    size_t i = ((size_t)blockIdx.x * 256 + threadIdx.x) * 4;
    *(f32x4*)(p + i) = f32x4{0.f, 0.f, 0.f, 0.f};
}

// ---------------------------------------------------------------------------
// u = Wk @ sk, w = Wv @ sv (fp32).  grid (1024, 2).
// ---------------------------------------------------------------------------
__global__ void bias_vec(const float* __restrict__ sk, const float* __restrict__ sv,
                         const float* __restrict__ Wk, const float* __restrict__ Wv,
                         float* __restrict__ u, float* __restrict__ w) {
    int gid = blockIdx.x * 4 + (threadIdx.x >> 6);   // 0..4095
    int lane = threadIdx.x & 63;
    int b = gid >> 10, d = gid & 1023;
    const float* W = blockIdx.y ? Wv : Wk;
    const float* s = blockIdx.y ? sv : sk;
    float* dst = blockIdx.y ? w : u;
    const float* wr = W + (size_t)d * 1024;
    const float* sr = s + b * 1024;
    float acc = 0.f;
    #pragma unroll
    for (int t = 0; t < 16; ++t) acc += wr[lane + t * 64] * sr[lane + t * 64];
    #pragma unroll
    for (int s2 = 32; s2; s2 >>= 1) acc += __shfl_xor(acc, s2, 64);
    if (lane == 0) dst[b * 1024 + d] = acc;
}

// ---------------------------------------------------------------------------
// ctx per head: ctx[dd][ee] = sum_k A3[h64+dd][k]*Wv[h64+ee][k] (double-f16)
//   + bk[d]*w[e] + bv[e]*u[d] + 4096*bk[d]*bv[e];  softmax over dd; *INV_QTR;
// store ctxT[bh][ee][dd] f16.  grid (64).
// ---------------------------------------------------------------------------
__global__ void ctx_gemm_softmax(const f16* __restrict__ a3hi, const f16* __restrict__ a3lo,
                                 const f16* __restrict__ wvhi, const f16* __restrict__ wvlo,
                                 const float* __restrict__ u, const float* __restrict__ wvec,
                                 const float* __restrict__ bk, const float* __restrict__ bv,
                                 f16* __restrict__ ctxT) {
    __shared__ __align__(16) f16 As0[64 * 64], As1[64 * 64], Bs0[64 * 64], Bs1[64 * 64];
    __shared__ float cs[64 * 65];
    int bh = blockIdx.x, b = bh >> 4, h = bh & 15;
    int tid = threadIdx.x, lane = tid & 63, wave = tid >> 6;
    const size_t abase = (size_t)b * 1048576 + (size_t)(h * 64) * 1024;
    const size_t wbase = (size_t)(h * 64) * 1024;
    int frow = lane & 15, quad = lane >> 4;
    f32x4 acc[4] = {};

    for (int k0 = 0; k0 < 1024; k0 += 64) {
        __syncthreads();
        #pragma unroll
        for (int i = 0; i < 2; ++i) {
            int slot = i * 256 + tid, row = slot >> 3, sc = slot & 7;
            int gc = sc ^ (row & 7);
            size_t ro = (size_t)row * 1024 + k0 + gc * 8;
            gload16(a3hi + abase + ro, (char*)As0 + slot * 16);
            gload16(a3lo + abase + ro, (char*)As1 + slot * 16);
            gload16(wvhi + wbase + ro, (char*)Bs0 + slot * 16);
            gload16(wvlo + wbase + ro, (char*)Bs1 + slot * 16);
        }
        __syncthreads();
        #pragma unroll
        for (int kk = 0; kk < 2; ++kk) {
            int arow = wave * 16 + frow;
            int asc  = (kk * 4 + quad) ^ (arow & 7);
            f16x8 fa0 = *(const f16x8*)(As0 + arow * 64 + asc * 8);
            f16x8 fa1 = *(const f16x8*)(As1 + arow * 64 + asc * 8);
            #pragma unroll
            for (int tn = 0; tn < 4; ++tn) {
                int brow = tn * 16 + frow;
                int bsc  = (kk * 4 + quad) ^ (brow & 7);
                f16x8 fb0 = *(const f16x8*)(Bs0 + brow * 64 + bsc * 8);
                f16x8 fb1 = *(const f16x8*)(Bs1 + brow * 64 + bsc * 8);
                acc[tn] = __builtin_amdgcn_mfma_f32_16x16x32_f16(fa0, fb0, acc[tn], 0, 0, 0);
                acc[tn] = __builtin_amdgcn_mfma_f32_16x16x32_f16(fa1, fb0, acc[tn], 0, 0, 0);
                acc[tn] = __builtin_amdgcn_mfma_f32_16x16x32_f16(fa0, fb1, acc[tn], 0, 0, 0);
            }
        }
    }

    const float* ub  = u + b * 1024 + h * 64;
    const float* wb  = wvec + b * 1024 + h * 64;
    const float* bkh = bk + h * 64;
    const float* bvh = bv + h * 64;
    #pragma unroll
    for (int tn = 0; tn < 4; ++tn) {
        int ee = tn * 16 + frow;
        float bve = bvh[ee], we = wb[ee];
        #pragma unroll
        for (int r = 0; r < 4; ++r) {
            int dd = wave * 16 + quad * 4 + r;
            float bkd = bkh[dd], ud = ub[dd];
            cs[dd * 65 + ee] = acc[tn][r] + bkd * we + bve * ud + 4096.0f * bkd * bve;
        }
    }
    __syncthreads();
    #pragma unroll
    for (int i = 0; i < 16; ++i) {
        int e = wave * 16 + i;
        float x = cs[lane * 65 + e];
        float m = x;
        #pragma unroll
        for (int s2 = 32; s2; s2 >>= 1) m = fmaxf(m, __shfl_xor(m, s2, 64));
        float ex = __expf(x - m);
        float sum = ex;
        #pragma unroll
        for (int s2 = 32; s2; s2 >>= 1) sum += __shfl_xor(sum, s2, 64);
        ctxT[((size_t)bh * 64 + e) * 64 + lane] = (f16)(ex / sum * INV_QTR);
    }
}

// ---------------------------------------------------------------------------
// att = qs @ ctx per head (block-diagonal, K=64). grid (128, 8). All f16.
// ---------------------------------------------------------------------------
__global__ void att_gemm(const f16* __restrict__ qs, const f16* __restrict__ ctxT,
                         f16* __restrict__ att) {
    __shared__ __align__(16) f16 As[2][128 * 64];
    __shared__ __align__(16) f16 Bs[2][64 * 64];
    int tid = threadIdx.x, lane = tid & 63, wave = tid >> 6;
    int m0 = blockIdx.x * 128;
    int n0 = blockIdx.y * 128;
    int b  = m0 >> 12;
    int h0 = (n0 >> 6) & 15;

    #pragma unroll
    for (int ch = 0; ch < 2; ++ch) {
        #pragma unroll
        for (int i = 0; i < 4; ++i) {
            int slot = i * 256 + tid, row = slot >> 3, sc = slot & 7, gc = sc ^ (row & 7);
            gload16(qs + (size_t)(m0 + row) * 1024 + n0 + ch * 64 + gc * 8,
                    (char*)As[ch] + slot * 16);
        }
        #pragma unroll
        for (int i = 0; i < 2; ++i) {
            int slot = i * 256 + tid, row = slot >> 3, sc = slot & 7, gc = sc ^ (row & 7);
            int bh = b * 16 + h0 + ch;
            gload16(ctxT + ((size_t)bh * 64 + row) * 64 + gc * 8,
                    (char*)Bs[ch] + slot * 16);
        }
    }
    __syncthreads();

    int wm = (wave >> 1) * 64, wn = wave & 1;
    int frow = lane & 15, quad = lane >> 4;
    f32x4 acc[4][4] = {};
    #pragma unroll
    for (int kk = 0; kk < 2; ++kk) {
        f16x8 fa[4], fb[4];
        #pragma unroll
        for (int t = 0; t < 4; ++t) {
            int arow = wm + t * 16 + frow;
            int asc  = (kk * 4 + quad) ^ (arow & 7);
            fa[t] = *(const f16x8*)(As[wn] + arow * 64 + asc * 8);
            int brow = t * 16 + frow;
            int bsc  = (kk * 4 + quad) ^ (brow & 7);
            fb[t] = *(const f16x8*)(Bs[wn] + brow * 64 + bsc * 8);
        }
        #pragma unroll
        for (int tm = 0; tm < 4; ++tm)
            #pragma unroll
            for (int tn = 0; tn < 4; ++tn)
                acc[tm][tn] = __builtin_amdgcn_mfma_f32_16x16x32_f16(
                    fa[tm], fb[tn], acc[tm][tn], 0, 0, 0);
    }
    #pragma unroll
    for (int tn = 0; tn < 4; ++tn) {
        int col = n0 + wn * 64 + tn * 16 + frow;
        #pragma unroll
        for (int tm = 0; tm < 4; ++tm) {
            #pragma unroll
            for (int r = 0; r < 4; ++r) {
                int row = m0 + wm + tm * 16 + quad * 4 + r;
                att[(size_t)row * 1024 + col] = (f16)acc[tm][tn][r];
            }
        }
    }
}

// ---------------------------------------------------------------------------
// cvt kernels
// ---------------------------------------------------------------------------
__device__ __forceinline__ void cvt8_hilo(const float* src, f16* dh, f16* dl, bool lo) {
    f32x4 a = ((const f32x4*)src)[0];
    f32x4 b = ((const f32x4*)src)[1];
    f16x8 h, l;
    #pragma unroll
    for (int j = 0; j < 4; ++j) {
        h[j] = (f16)a[j];     h[j + 4] = (f16)b[j];
        l[j] = (f16)(a[j] - (float)h[j]);
        l[j + 4] = (f16)(b[j] - (float)h[j + 4]);
    }
    *(f16x8*)dh = h;
    if (lo) *(f16x8*)dl = l;
}

// Wk, Wv -> hi + lo f16.  grid (512, 2).
__global__ void cvt_w_kv(const float* __restrict__ Wk, const float* __restrict__ Wv,
                         f16* __restrict__ whik, f16* __restrict__ whiv,
                         f16* __restrict__ wlok, f16* __restrict__ wlov) {
    const float* s = blockIdx.y ? Wv : Wk;
    f16* dh = blockIdx.y ? whiv : whik;
    f16* dl = blockIdx.y ? wlov : wlok;
    size_t i = ((size_t)blockIdx.x * 256 + threadIdx.x) * 8;
    cvt8_hilo(s + i, dh + i, dl + i, true);
}

// q -> f16; Wq, Wo -> hi f16.  grid (9216).
__global__ void cvt_q_wqo(const float* __restrict__ q, const float* __restrict__ Wq,
                          const float* __restrict__ Wo, f16* __restrict__ qh,
                          f16* __restrict__ wqhi, f16* __restrict__ wohi) {
    size_t i = ((size_t)blockIdx.x * 256 + threadIdx.x) * 8;
    const float* src;
    f16* dst;
    if (i < 16777216) { src = q + i; dst = qh + i; }
    else {
        size_t wi = i - 16777216;
        if (wi < 1048576) { src = Wq + wi; dst = wqhi + wi; }
        else              { src = Wo + (wi - 1048576); dst = wohi + (wi - 1048576); }
    }
    cvt8_hilo(src, dst, nullptr, false);
}

// ---------------------------------------------------------------------------
// Buffer plan (Mi = 1<<20 bytes; ws peak = 76Mi):
// ws:  0-8    Ghi (after XvTh dead)        32-48  G0 fp32 -> Wqhi@32, Wohi@34
//      8-16   Glo                          48-64  G1 fp32
//      16-24  A3hi (XvTh dead)             64-72  Wkhi|Wvhi|Wklo|Wvlo
//      24-32  A3lo                         36-68  att (after ctx done)
//      72Mi   ctxT (512Ki); +512Ki sk(16Ki) sv(16Ki) u(16Ki) w(16Ki)
//      XvTh = ws+0..32 (dead after gram1)
// d_out: XkTh 0-32 | XkTl->XvTl 32-64  ->  P0 0-16 | P1 16-32
//        -> qh 0-32 | qp 32-64 -> final fp32 out 0-64.
// ---------------------------------------------------------------------------
extern "C" void kernel_launch(void* const* d_in, const int* in_sizes, int n_in,
                              void* d_out, int out_size, void* d_ws, size_t ws_size,
                              hipStream_t stream) {
    const float* q  = (const float*)d_in[0];
    const float* k  = (const float*)d_in[1];
    const float* v  = (const float*)d_in[2];
    const float* Wq = (const float*)d_in[3];
    const float* bq = (const float*)d_in[4];
    const float* Wk = (const float*)d_in[5];
    const float* bk = (const float*)d_in[6];
    const float* Wv = (const float*)d_in[7];
    const float* bv = (const float*)d_in[8];
    const float* Wo = (const float*)d_in[9];

    const size_t Mi = 1048576;
    char* ws = (char*)d_ws;
    char* ob = (char*)d_out;

    f16*   Ghi  = (f16*)ws;                       // 0-8
    f16*   Glo  = (f16*)(ws + 8 * Mi);            // 8-16
    f16*   A3hi = (f16*)(ws + 16 * Mi);           // 16-24
    f16*   A3lo = (f16*)(ws + 24 * Mi);           // 24-32
    float* G0   = (float*)(ws + 32 * Mi);         // 32-48
    float* G1   = (float*)(ws + 48 * Mi);         // 48-64
    f16*   Wkhi = (f16*)(ws + 64 * Mi);
    f16*   Wvhi = (f16*)(ws + 66 * Mi);
    f16*   Wklo = (f16*)(ws + 68 * Mi);
    f16*   Wvlo = (f16*)(ws + 70 * Mi);
    f16*   ctxT = (f16*)(ws + 72 * Mi);           // 512 Ki
    float* sk   = (float*)(ws + 72 * Mi + 524288);
    float* sv   = (float*)(ws + 72 * Mi + 540672);
    float* u    = (float*)(ws + 72 * Mi + 557056);
    float* w    = (float*)(ws + 72 * Mi + 573440);
    f16*   XvTh = (f16*)ws;                       // 0-32, dead after gram1
    f16*   Wqhi = (f16*)(ws + 32 * Mi);           // after G0 dead
    f16*   Wohi = (f16*)(ws + 34 * Mi);
    f16*   att  = (f16*)(ws + 36 * Mi);           // 36-68, after ctx done

    f16*   XkTh = (f16*)ob;                       // 0-32
    f16*   XkTl = (f16*)(ob + 32 * Mi);
    f16*   XvTl = (f16*)(ob + 32 * Mi);           // after gram1
    float* P0   = (float*)ob;                     // 0-16, after gram2
    float* P1   = (float*)(ob + 16 * Mi);         // 16-32
    f16*   qh   = (f16*)ob;                       // after a3_combine
    f16*   qp   = (f16*)(ob + 32 * Mi);
    float* out  = (float*)d_out;

    // zero atomic colsum targets (sk|sv contiguous, 8192 floats)
    zero_f32<<<8, 256, 0, stream>>>(sk);
    // weights hi/lo for the high-precision ctx path
    cvt_w_kv<<<dim3(512, 2), 256, 0, stream>>>(Wk, Wv, Wkhi, Wvhi, Wklo, Wvlo);
    // transposed hi/lo inputs + fused column sums
    transpose_cvt<0, true><<<dim3(64, 16, 4), 256, 0, stream>>>(k, XkTh, XkTl, sk);
    transpose_cvt<1, true><<<dim3(64, 16, 4), 256, 0, stream>>>(v, XvTh, nullptr, sv);
    // G' = Xv^T Xk, double-f16: hi*(hi+lo) then + lo*hi
    gram_gemm<2, false><<<dim3(8, 8, 8), 256, 0, stream>>>(XvTh, XkTh, XkTl, G0, G1);
    transpose_cvt<2, false><<<dim3(64, 16, 4), 256, 0, stream>>>(v, XvTl, nullptr, nullptr);
    gram_gemm<1, true><<<dim3(8, 8, 8), 256, 0, stream>>>(XvTl, XkTh, nullptr, G0, G1);
    // G -> f16 hi/lo (coalesced), then all-f16 K-split a3, then combine
    combine_split<<<2048, 256, 0, stream>>>(G0, G1, Ghi, Glo);
    a3f16_gemm<<<dim3(8, 8, 8), 256, 0, stream>>>(Wkhi, Wklo, Ghi, Glo, P0, P1);
    combine_split<<<2048, 256, 0, stream>>>(P0, P1, A3hi, A3lo);
    // rank-1 bias terms
    bias_vec<<<dim3(1024, 2), 256, 0, stream>>>(sk, sv, Wk, Wv, u, w);
    // ctx + softmax -> ctxT
    ctx_gemm_softmax<<<64, 256, 0, stream>>>(A3hi, A3lo, Wvhi, Wvlo, u, w, bk, bv, ctxT);
    // Q path (f16 sufficient: feature softmax bounds sensitivity)
    cvt_q_wqo<<<9216, 256, 0, stream>>>(q, Wq, Wo, qh, Wqhi, Wohi);
    proj_qsm_gemm<<<dim3(128, 8), 256, 0, stream>>>(qh, Wqhi, bq, qp);
    att_gemm<<<dim3(128, 8), 256, 0, stream>>>(qp, ctxT, att);
    out_gemm<<<dim3(128, 8), 256, 0, stream>>>(att, Wohi, out);
}

// Round 5
// 597.138 us; speedup vs baseline: 1.2678x; 1.0611x over previous
//
#include <hip/hip_runtime.h>

#define INV_QTR 0.59460355750136053f   // 8^(-1/4)

typedef _Float16 f16;
typedef _Float16 f16x8 __attribute__((ext_vector_type(8)));
typedef float f32x4 __attribute__((ext_vector_type(4)));

__device__ __forceinline__ void gload16(const void* g, void* l) {
    __builtin_amdgcn_global_load_lds(
        (const __attribute__((address_space(1))) void*)g,
        (__attribute__((address_space(3))) void*)l, 16, 0, 0);
}

// ---------------------------------------------------------------------------
// All-f16 BT-GEMM (m97 structure): dst[m][n] = sum_k X[m][k]*W[n][k] (+bias).
// 128x128 tile, BK=64, global_load_lds width=16, XOR swizzle on 16B chunks,
// 16x16x32 f16 MFMA, fp32 accum.
// QSM: fused feature-softmax over the 64-wide head group + *INV_QTR (Q path).
// ---------------------------------------------------------------------------
template <bool OF, bool BIAS, bool QSM>
__device__ __forceinline__ void gemm_f16_body(const f16* __restrict__ X,
                                              const f16* __restrict__ W,
                                              const float* __restrict__ bias,
                                              void* __restrict__ dst) {
    __shared__ __align__(16) f16 As[128 * 64];
    __shared__ __align__(16) f16 Bs[128 * 64];

    const int tid  = threadIdx.x;
    const int lane = tid & 63;
    const int wave = tid >> 6;
    const int m0   = blockIdx.x * 128;
    const int n0   = blockIdx.y * 128;
    const int wm   = (wave >> 1) * 64;
    const int wn   = (wave & 1) * 64;
    const int frow = lane & 15;
    const int quad = lane >> 4;

    f32x4 acc[4][4] = {};

    for (int k0 = 0; k0 < 1024; k0 += 64) {
        __syncthreads();
        #pragma unroll
        for (int i = 0; i < 4; ++i) {
            int slot = i * 256 + tid;
            int row  = slot >> 3;
            int sc   = slot & 7;
            int gc   = sc ^ (row & 7);
            gload16(X + (size_t)(m0 + row) * 1024 + k0 + gc * 8,
                    (char*)As + slot * 16);
            gload16(W + (size_t)(n0 + row) * 1024 + k0 + gc * 8,
                    (char*)Bs + slot * 16);
        }
        __syncthreads();

        #pragma unroll
        for (int kk = 0; kk < 2; ++kk) {
            f16x8 fa[4], fb[4];
            #pragma unroll
            for (int t = 0; t < 4; ++t) {
                int arow = wm + t * 16 + frow;
                int asc  = (kk * 4 + quad) ^ (arow & 7);
                fa[t] = *(const f16x8*)(As + arow * 64 + asc * 8);
                int brow = wn + t * 16 + frow;
                int bsc  = (kk * 4 + quad) ^ (brow & 7);
                fb[t] = *(const f16x8*)(Bs + brow * 64 + bsc * 8);
            }
            #pragma unroll
            for (int tm = 0; tm < 4; ++tm)
                #pragma unroll
                for (int tn = 0; tn < 4; ++tn)
                    acc[tm][tn] = __builtin_amdgcn_mfma_f32_16x16x32_f16(
                        fa[tm], fb[tn], acc[tm][tn], 0, 0, 0);
        }
    }

    if (QSM) {
        // Each row's 64 head values: tn regs x 16 frow lanes (within quad).
        float badd[4];
        #pragma unroll
        for (int tn = 0; tn < 4; ++tn) badd[tn] = bias[n0 + wn + tn * 16 + frow];
        #pragma unroll
        for (int tm = 0; tm < 4; ++tm) {
            #pragma unroll
            for (int r = 0; r < 4; ++r) {
                float x[4], m = -1e30f;
                #pragma unroll
                for (int tn = 0; tn < 4; ++tn) {
                    x[tn] = acc[tm][tn][r] + badd[tn];
                    m = fmaxf(m, x[tn]);
                }
                #pragma unroll
                for (int s = 1; s < 16; s <<= 1) m = fmaxf(m, __shfl_xor(m, s, 64));
                float e[4], sum = 0.f;
                #pragma unroll
                for (int tn = 0; tn < 4; ++tn) { e[tn] = __expf(x[tn] - m); sum += e[tn]; }
                #pragma unroll
                for (int s = 1; s < 16; s <<= 1) sum += __shfl_xor(sum, s, 64);
                float inv = INV_QTR / sum;
                size_t rowb = (size_t)(m0 + wm + tm * 16 + quad * 4 + r) * 1024;
                #pragma unroll
                for (int tn = 0; tn < 4; ++tn)
                    ((f16*)dst)[rowb + n0 + wn + tn * 16 + frow] = (f16)(e[tn] * inv);
            }
        }
        return;
    }

    #pragma unroll
    for (int tn = 0; tn < 4; ++tn) {
        int col = n0 + wn + tn * 16 + frow;
        float badd = BIAS ? bias[col] : 0.0f;
        #pragma unroll
        for (int tm = 0; tm < 4; ++tm) {
            #pragma unroll
            for (int r = 0; r < 4; ++r) {
                size_t idx = (size_t)(m0 + wm + tm * 16 + quad * 4 + r) * 1024 + col;
                float v = acc[tm][tn][r] + badd;
                if (OF) ((float*)dst)[idx] = v;
                else    ((f16*)dst)[idx] = (f16)v;
            }
        }
    }
}

// Q projection with fused feature-softmax.  grid (128, 8).
__global__ void proj_qsm_gemm(const f16* __restrict__ X, const f16* __restrict__ W,
                              const float* __restrict__ bias, f16* __restrict__ dst) {
    gemm_f16_body<false, true, true>(X, W, bias, dst);
}

// out = att @ Wo^T (no bias), fp32 out.  grid (128, 8).
__global__ void out_gemm(const f16* __restrict__ att, const f16* __restrict__ Wo,
                         float* __restrict__ out) {
    gemm_f16_body<true, false, false>(att, Wo, nullptr, out);
}

// ---------------------------------------------------------------------------
// Transpose + fp32->f16 hi/lo split: src [4][4096][1024] f32 -> dstT [4][1024][4096].
// MODE 0: dst0=hi, dst1=lo.  MODE 1: dst0=hi only.  MODE 2: dst0=lo only.
// CS: fold column-sum (over n) into csum[b*1024+c] via one atomicAdd/block/col.
// ---------------------------------------------------------------------------
template <int MODE, bool CS>
__global__ void transpose_cvt(const float* __restrict__ src, f16* __restrict__ dst0,
                              f16* __restrict__ dst1, float* __restrict__ csum) {
    __shared__ float T[64][65];
    int n0 = blockIdx.x * 64, c0 = blockIdx.y * 64, b = blockIdx.z;
    int tid = threadIdx.x;
    const float* s = src + ((size_t)b * 4096 + n0) * 1024 + c0;
    int r = tid >> 2, q4 = tid & 3;
    #pragma unroll
    for (int i = 0; i < 4; ++i) {
        f32x4 v = *(const f32x4*)(s + (size_t)r * 1024 + q4 * 16 + i * 4);
        #pragma unroll
        for (int j = 0; j < 4; ++j) T[q4 * 16 + i * 4 + j][r] = v[j];
    }
    __syncthreads();
    int cc = tid >> 2, nq = tid & 3;
    size_t obase = ((size_t)b * 1024 + c0 + cc) * 4096 + n0 + nq * 16;
    float x[16];
    #pragma unroll
    for (int j = 0; j < 16; ++j) x[j] = T[cc][nq * 16 + j];
    if (CS) {
        float ssum = 0.f;
        #pragma unroll
        for (int j = 0; j < 16; ++j) ssum += x[j];
        ssum += __shfl_xor(ssum, 1, 64);
        ssum += __shfl_xor(ssum, 2, 64);
        if (nq == 0) atomicAdd(csum + b * 1024 + c0 + cc, ssum);
    }
    f16x8 hi0, hi1;
    #pragma unroll
    for (int j = 0; j < 8; ++j) { hi0[j] = (f16)x[j]; hi1[j] = (f16)x[8 + j]; }
    if (MODE == 0 || MODE == 1) {
        *(f16x8*)(dst0 + obase) = hi0;
        *(f16x8*)(dst0 + obase + 8) = hi1;
    }
    if (MODE == 0 || MODE == 2) {
        f16x8 lo0, lo1;
        #pragma unroll
        for (int j = 0; j < 8; ++j) {
            lo0[j] = (f16)(x[j] - (float)hi0[j]);
            lo1[j] = (f16)(x[8 + j] - (float)hi1[j]);
        }
        f16* d = (MODE == 0) ? dst1 : dst0;
        *(f16x8*)(d + obase) = lo0;
        *(f16x8*)(d + obase + 8) = lo1;
    }
}

// ---------------------------------------------------------------------------
// Gram GEMM: G'[p][q] = sum_n XvT[p][n]*XkT[q][n]  (= (Xv^T Xk)[p,q] = G^T).
// Grid (8 zsel, 8 m, 8 n), zsel = b*2 + khalf on blockIdx.x: XCD = bid%8 =
// zsel, so each XCD owns one (b,kh) slice's 64 tiles -> per-XCD L2 working
// set 12 MiB, K-window L2-resident (fetch-bound fix, T1-style).
// NB==2: acc += A*(B0+B1) (hi*(hi+lo));  ACCUM: read-modify-write fp32 out.
// ---------------------------------------------------------------------------
template <int NB, bool ACCUM>
__global__ void gram_gemm(const f16* __restrict__ A, const f16* __restrict__ B0,
                          const f16* __restrict__ B1, float* __restrict__ G0,
                          float* __restrict__ G1) {
    __shared__ __align__(16) f16 As[128 * 64];
    __shared__ __align__(16) f16 Bs0[128 * 64];
    __shared__ __align__(16) f16 Bs1[NB == 2 ? 128 * 64 : 8];
    const int tid = threadIdx.x, lane = tid & 63, wave = tid >> 6;
    const int zsel = blockIdx.x;                    // z-first: XCD = zsel
    const int m0 = blockIdx.y * 128, n0 = blockIdx.z * 128;
    const int b = zsel >> 1, kh = zsel & 1;
    const int wm = (wave >> 1) * 64, wn = (wave & 1) * 64;
    const int frow = lane & 15, quad = lane >> 4;
    const f16* Ab  = A + (size_t)b * 4194304;
    const f16* B0b = B0 + (size_t)b * 4194304;
    const f16* B1b = (NB == 2) ? B1 + (size_t)b * 4194304 : nullptr;
    float* Gd = (kh ? G1 : G0) + (size_t)b * 1048576;
    const int kbase = kh * 2048;
    f32x4 acc[4][4] = {};

    for (int k0 = kbase; k0 < kbase + 2048; k0 += 64) {
        __syncthreads();
        #pragma unroll
        for (int i = 0; i < 4; ++i) {
            int slot = i * 256 + tid, row = slot >> 3, sc = slot & 7;
            int gc = sc ^ (row & 7);
            gload16(Ab + (size_t)(m0 + row) * 4096 + k0 + gc * 8, (char*)As + slot * 16);
            gload16(B0b + (size_t)(n0 + row) * 4096 + k0 + gc * 8, (char*)Bs0 + slot * 16);
            if (NB == 2)
                gload16(B1b + (size_t)(n0 + row) * 4096 + k0 + gc * 8, (char*)Bs1 + slot * 16);
        }
        __syncthreads();
        #pragma unroll
        for (int kk = 0; kk < 2; ++kk) {
            f16x8 fa[4], fb0[4], fb1[4];
            #pragma unroll
            for (int t = 0; t < 4; ++t) {
                int arow = wm + t * 16 + frow;
                int asc  = (kk * 4 + quad) ^ (arow & 7);
                fa[t] = *(const f16x8*)(As + arow * 64 + asc * 8);
                int brow = wn + t * 16 + frow;
                int bsc  = (kk * 4 + quad) ^ (brow & 7);
                fb0[t] = *(const f16x8*)(Bs0 + brow * 64 + bsc * 8);
                if (NB == 2) fb1[t] = *(const f16x8*)(Bs1 + brow * 64 + bsc * 8);
            }
            #pragma unroll
            for (int tm = 0; tm < 4; ++tm)
                #pragma unroll
                for (int tn = 0; tn < 4; ++tn) {
                    acc[tm][tn] = __builtin_amdgcn_mfma_f32_16x16x32_f16(
                        fa[tm], fb0[tn], acc[tm][tn], 0, 0, 0);
                    if (NB == 2)
                        acc[tm][tn] = __builtin_amdgcn_mfma_f32_16x16x32_f16(
                            fa[tm], fb1[tn], acc[tm][tn], 0, 0, 0);
                }
        }
    }
    #pragma unroll
    for (int tn = 0; tn < 4; ++tn) {
        int col = n0 + wn + tn * 16 + frow;
        #pragma unroll
        for (int tm = 0; tm < 4; ++tm)
            #pragma unroll
            for (int r = 0; r < 4; ++r) {
                size_t idx = (size_t)(m0 + wm + tm * 16 + quad * 4 + r) * 1024 + col;
                if (ACCUM) Gd[idx] += acc[tm][tn][r];
                else       Gd[idx]  = acc[tm][tn][r];
            }
    }
}

// ---------------------------------------------------------------------------
// combine_split: hi/lo f16 split of (a[i]+b[i]).  8 elems/thread.
// Used for G0+G1 -> Ghi/Glo and P0+P1 -> A3hi/A3lo (coalesced f16x8 stores).
// ---------------------------------------------------------------------------
__global__ void combine_split(const float* __restrict__ a, const float* __restrict__ b,
                              f16* __restrict__ hi, f16* __restrict__ lo) {
    size_t i = ((size_t)blockIdx.x * 256 + threadIdx.x) * 8;
    f32x4 a0 = *(const f32x4*)(a + i);
    f32x4 a1 = *(const f32x4*)(a + i + 4);
    f32x4 b0 = *(const f32x4*)(b + i);
    f32x4 b1 = *(const f32x4*)(b + i + 4);
    f16x8 h, l;
    #pragma unroll
    for (int j = 0; j < 4; ++j) {
        float s0 = a0[j] + b0[j], s1 = a1[j] + b1[j];
        h[j] = (f16)s0;     l[j] = (f16)(s0 - (float)h[j]);
        h[4 + j] = (f16)s1; l[4 + j] = (f16)(s1 - (float)h[4 + j]);
    }
    *(f16x8*)(hi + i) = h;
    *(f16x8*)(lo + i) = l;
}

// ---------------------------------------------------------------------------
// a3 = Wk @ G' (3-term double-f16, all panels via global_load_lds).
// Grid (8 zsel, 8 m, 8 n), zsel = b*2+kh: XCD = zsel, per-XCD working set
// 4 MiB (Wk kh-half + G batch/kh slice).  Writes fp32 partials P0/P1; no RMW.
// ---------------------------------------------------------------------------
__global__ void a3f16_gemm(const f16* __restrict__ wkhi, const f16* __restrict__ wklo,
                           const f16* __restrict__ ghi, const f16* __restrict__ glo,
                           float* __restrict__ P0, float* __restrict__ P1) {
    __shared__ __align__(16) f16 As0[128 * 64], As1[128 * 64];
    __shared__ __align__(16) f16 Bs0[128 * 64], Bs1[128 * 64];
    const int tid = threadIdx.x, lane = tid & 63, wave = tid >> 6;
    const int zsel = blockIdx.x;                    // z-first: XCD = zsel
    const int m0 = blockIdx.y * 128, n0 = blockIdx.z * 128;
    const int b = zsel >> 1, kh = zsel & 1;
    const int wm = (wave >> 1) * 64, wn = (wave & 1) * 64;
    const int frow = lane & 15, quad = lane >> 4;
    const f16* g0b = ghi + (size_t)b * 1048576;
    const f16* g1b = glo + (size_t)b * 1048576;
    float* Pd = (kh ? P1 : P0) + (size_t)b * 1048576;
    const int kbase = kh * 512;
    f32x4 acc[4][4] = {};

    for (int k0 = kbase; k0 < kbase + 512; k0 += 64) {
        __syncthreads();
        #pragma unroll
        for (int i = 0; i < 4; ++i) {
            int slot = i * 256 + tid, row = slot >> 3, sc = slot & 7;
            int gc = sc ^ (row & 7);
            size_t ao = (size_t)(m0 + row) * 1024 + k0 + gc * 8;
            size_t bo = (size_t)(n0 + row) * 1024 + k0 + gc * 8;
            gload16(wkhi + ao, (char*)As0 + slot * 16);
            gload16(wklo + ao, (char*)As1 + slot * 16);
            gload16(g0b + bo, (char*)Bs0 + slot * 16);
            gload16(g1b + bo, (char*)Bs1 + slot * 16);
        }
        __syncthreads();
        #pragma unroll
        for (int kk = 0; kk < 2; ++kk) {
            f16x8 fa0[4], fa1[4], fb0[4], fb1[4];
            #pragma unroll
            for (int t = 0; t < 4; ++t) {
                int arow = wm + t * 16 + frow;
                int asc  = (kk * 4 + quad) ^ (arow & 7);
                fa0[t] = *(const f16x8*)(As0 + arow * 64 + asc * 8);
                fa1[t] = *(const f16x8*)(As1 + arow * 64 + asc * 8);
                int brow = wn + t * 16 + frow;
                int bsc  = (kk * 4 + quad) ^ (brow & 7);
                fb0[t] = *(const f16x8*)(Bs0 + brow * 64 + bsc * 8);
                fb1[t] = *(const f16x8*)(Bs1 + brow * 64 + bsc * 8);
            }
            #pragma unroll
            for (int tm = 0; tm < 4; ++tm)
                #pragma unroll
                for (int tn = 0; tn < 4; ++tn) {
                    acc[tm][tn] = __builtin_amdgcn_mfma_f32_16x16x32_f16(
                        fa0[tm], fb0[tn], acc[tm][tn], 0, 0, 0);
                    acc[tm][tn] = __builtin_amdgcn_mfma_f32_16x16x32_f16(
                        fa1[tm], fb0[tn], acc[tm][tn], 0, 0, 0);
                    acc[tm][tn] = __builtin_amdgcn_mfma_f32_16x16x32_f16(
                        fa0[tm], fb1[tn], acc[tm][tn], 0, 0, 0);
                }
        }
    }
    #pragma unroll
    for (int tn = 0; tn < 4; ++tn) {
        int col = n0 + wn + tn * 16 + frow;
        #pragma unroll
        for (int tm = 0; tm < 4; ++tm)
            #pragma unroll
            for (int r = 0; r < 4; ++r)
                Pd[(size_t)(m0 + wm + tm * 16 + quad * 4 + r) * 1024 + col] =
                    acc[tm][tn][r];
    }
}

// ---------------------------------------------------------------------------
// zero 8192 floats (sk|sv) for the atomic column sums.  grid (8).
// ---------------------------------------------------------------------------
__global__ void zero_f32(float* __restrict__ p) {
    size_t i = ((size_t)blockIdx.x * 256 + threadIdx.x) * 4;
    *(f32x4*)(p + i) = f32x4{0.f, 0.f, 0.f, 0.f};
}

// ---------------------------------------------------------------------------
// u = Wk @ sk, w = Wv @ sv (fp32).  grid (1024, 2).
// ---------------------------------------------------------------------------
__global__ void bias_vec(const float* __restrict__ sk, const float* __restrict__ sv,
                         const float* __restrict__ Wk, const float* __restrict__ Wv,
                         float* __restrict__ u, float* __restrict__ w) {
    int gid = blockIdx.x * 4 + (threadIdx.x >> 6);   // 0..4095
    int lane = threadIdx.x & 63;
    int b = gid >> 10, d = gid & 1023;
    const float* W = blockIdx.y ? Wv : Wk;
    const float* s = blockIdx.y ? sv : sk;
    float* dst = blockIdx.y ? w : u;
    const float* wr = W + (size_t)d * 1024;
    const float* sr = s + b * 1024;
    float acc = 0.f;
    #pragma unroll
    for (int t = 0; t < 16; ++t) acc += wr[lane + t * 64] * sr[lane + t * 64];
    #pragma unroll
    for (int s2 = 32; s2; s2 >>= 1) acc += __shfl_xor(acc, s2, 64);
    if (lane == 0) dst[b * 1024 + d] = acc;
}

// ---------------------------------------------------------------------------
// ctx per head: ctx[dd][ee] = sum_k A3[h64+dd][k]*Wv[h64+ee][k] (double-f16)
//   + bk[d]*w[e] + bv[e]*u[d] + 4096*bk[d]*bv[e];  softmax over dd; *INV_QTR;
// store ctxT[bh][ee][dd] f16.  grid (64).
// ---------------------------------------------------------------------------
__global__ void ctx_gemm_softmax(const f16* __restrict__ a3hi, const f16* __restrict__ a3lo,
                                 const f16* __restrict__ wvhi, const f16* __restrict__ wvlo,
                                 const float* __restrict__ u, const float* __restrict__ wvec,
                                 const float* __restrict__ bk, const float* __restrict__ bv,
                                 f16* __restrict__ ctxT) {
    __shared__ __align__(16) f16 As0[64 * 64], As1[64 * 64], Bs0[64 * 64], Bs1[64 * 64];
    __shared__ float cs[64 * 65];
    int bh = blockIdx.x, b = bh >> 4, h = bh & 15;
    int tid = threadIdx.x, lane = tid & 63, wave = tid >> 6;
    const size_t abase = (size_t)b * 1048576 + (size_t)(h * 64) * 1024;
    const size_t wbase = (size_t)(h * 64) * 1024;
    int frow = lane & 15, quad = lane >> 4;
    f32x4 acc[4] = {};

    for (int k0 = 0; k0 < 1024; k0 += 64) {
        __syncthreads();
        #pragma unroll
        for (int i = 0; i < 2; ++i) {
            int slot = i * 256 + tid, row = slot >> 3, sc = slot & 7;
            int gc = sc ^ (row & 7);
            size_t ro = (size_t)row * 1024 + k0 + gc * 8;
            gload16(a3hi + abase + ro, (char*)As0 + slot * 16);
            gload16(a3lo + abase + ro, (char*)As1 + slot * 16);
            gload16(wvhi + wbase + ro, (char*)Bs0 + slot * 16);
            gload16(wvlo + wbase + ro, (char*)Bs1 + slot * 16);
        }
        __syncthreads();
        #pragma unroll
        for (int kk = 0; kk < 2; ++kk) {
            int arow = wave * 16 + frow;
            int asc  = (kk * 4 + quad) ^ (arow & 7);
            f16x8 fa0 = *(const f16x8*)(As0 + arow * 64 + asc * 8);
            f16x8 fa1 = *(const f16x8*)(As1 + arow * 64 + asc * 8);
            #pragma unroll
            for (int tn = 0; tn < 4; ++tn) {
                int brow = tn * 16 + frow;
                int bsc  = (kk * 4 + quad) ^ (brow & 7);
                f16x8 fb0 = *(const f16x8*)(Bs0 + brow * 64 + bsc * 8);
                f16x8 fb1 = *(const f16x8*)(Bs1 + brow * 64 + bsc * 8);
                acc[tn] = __builtin_amdgcn_mfma_f32_16x16x32_f16(fa0, fb0, acc[tn], 0, 0, 0);
                acc[tn] = __builtin_amdgcn_mfma_f32_16x16x32_f16(fa1, fb0, acc[tn], 0, 0, 0);
                acc[tn] = __builtin_amdgcn_mfma_f32_16x16x32_f16(fa0, fb1, acc[tn], 0, 0, 0);
            }
        }
    }

    const float* ub  = u + b * 1024 + h * 64;
    const float* wb  = wvec + b * 1024 + h * 64;
    const float* bkh = bk + h * 64;
    const float* bvh = bv + h * 64;
    #pragma unroll
    for (int tn = 0; tn < 4; ++tn) {
        int ee = tn * 16 + frow;
        float bve = bvh[ee], we = wb[ee];
        #pragma unroll
        for (int r = 0; r < 4; ++r) {
            int dd = wave * 16 + quad * 4 + r;
            float bkd = bkh[dd], ud = ub[dd];
            cs[dd * 65 + ee] = acc[tn][r] + bkd * we + bve * ud + 4096.0f * bkd * bve;
        }
    }
    __syncthreads();
    #pragma unroll
    for (int i = 0; i < 16; ++i) {
        int e = wave * 16 + i;
        float x = cs[lane * 65 + e];
        float m = x;
        #pragma unroll
        for (int s2 = 32; s2; s2 >>= 1) m = fmaxf(m, __shfl_xor(m, s2, 64));
        float ex = __expf(x - m);
        float sum = ex;
        #pragma unroll
        for (int s2 = 32; s2; s2 >>= 1) sum += __shfl_xor(sum, s2, 64);
        ctxT[((size_t)bh * 64 + e) * 64 + lane] = (f16)(ex / sum * INV_QTR);
    }
}

// ---------------------------------------------------------------------------
// att = qs @ ctx per head (block-diagonal, K=64). grid (128, 8). All f16.
// ---------------------------------------------------------------------------
__global__ void att_gemm(const f16* __restrict__ qs, const f16* __restrict__ ctxT,
                         f16* __restrict__ att) {
    __shared__ __align__(16) f16 As[2][128 * 64];
    __shared__ __align__(16) f16 Bs[2][64 * 64];
    int tid = threadIdx.x, lane = tid & 63, wave = tid >> 6;
    int m0 = blockIdx.x * 128;
    int n0 = blockIdx.y * 128;
    int b  = m0 >> 12;
    int h0 = (n0 >> 6) & 15;

    #pragma unroll
    for (int ch = 0; ch < 2; ++ch) {
        #pragma unroll
        for (int i = 0; i < 4; ++i) {
            int slot = i * 256 + tid, row = slot >> 3, sc = slot & 7, gc = sc ^ (row & 7);
            gload16(qs + (size_t)(m0 + row) * 1024 + n0 + ch * 64 + gc * 8,
                    (char*)As[ch] + slot * 16);
        }
        #pragma unroll
        for (int i = 0; i < 2; ++i) {
            int slot = i * 256 + tid, row = slot >> 3, sc = slot & 7, gc = sc ^ (row & 7);
            int bh = b * 16 + h0 + ch;
            gload16(ctxT + ((size_t)bh * 64 + row) * 64 + gc * 8,
                    (char*)Bs[ch] + slot * 16);
        }
    }
    __syncthreads();

    int wm = (wave >> 1) * 64, wn = wave & 1;
    int frow = lane & 15, quad = lane >> 4;
    f32x4 acc[4][4] = {};
    #pragma unroll
    for (int kk = 0; kk < 2; ++kk) {
        f16x8 fa[4], fb[4];
        #pragma unroll
        for (int t = 0; t < 4; ++t) {
            int arow = wm + t * 16 + frow;
            int asc  = (kk * 4 + quad) ^ (arow & 7);
            fa[t] = *(const f16x8*)(As[wn] + arow * 64 + asc * 8);
            int brow = t * 16 + frow;
            int bsc  = (kk * 4 + quad) ^ (brow & 7);
            fb[t] = *(const f16x8*)(Bs[wn] + brow * 64 + bsc * 8);
        }
        #pragma unroll
        for (int tm = 0; tm < 4; ++tm)
            #pragma unroll
            for (int tn = 0; tn < 4; ++tn)
                acc[tm][tn] = __builtin_amdgcn_mfma_f32_16x16x32_f16(
                    fa[tm], fb[tn], acc[tm][tn], 0, 0, 0);
    }
    #pragma unroll
    for (int tn = 0; tn < 4; ++tn) {
        int col = n0 + wn * 64 + tn * 16 + frow;
        #pragma unroll
        for (int tm = 0; tm < 4; ++tm) {
            #pragma unroll
            for (int r = 0; r < 4; ++r) {
                int row = m0 + wm + tm * 16 + quad * 4 + r;
                att[(size_t)row * 1024 + col] = (f16)acc[tm][tn][r];
            }
        }
    }
}

// ---------------------------------------------------------------------------
// cvt kernels
// ---------------------------------------------------------------------------
__device__ __forceinline__ void cvt8_hilo(const float* src, f16* dh, f16* dl, bool lo) {
    f32x4 a = ((const f32x4*)src)[0];
    f32x4 b = ((const f32x4*)src)[1];
    f16x8 h, l;
    #pragma unroll
    for (int j = 0; j < 4; ++j) {
        h[j] = (f16)a[j];     h[j + 4] = (f16)b[j];
        l[j] = (f16)(a[j] - (float)h[j]);
        l[j + 4] = (f16)(b[j] - (float)h[j + 4]);
    }
    *(f16x8*)dh = h;
    if (lo) *(f16x8*)dl = l;
}

// Wk, Wv -> hi + lo f16.  grid (512, 2).
__global__ void cvt_w_kv(const float* __restrict__ Wk, const float* __restrict__ Wv,
                         f16* __restrict__ whik, f16* __restrict__ whiv,
                         f16* __restrict__ wlok, f16* __restrict__ wlov) {
    const float* s = blockIdx.y ? Wv : Wk;
    f16* dh = blockIdx.y ? whiv : whik;
    f16* dl = blockIdx.y ? wlov : wlok;
    size_t i = ((size_t)blockIdx.x * 256 + threadIdx.x) * 8;
    cvt8_hilo(s + i, dh + i, dl + i, true);
}

// q -> f16; Wq, Wo -> hi f16.  grid (9216).
__global__ void cvt_q_wqo(const float* __restrict__ q, const float* __restrict__ Wq,
                          const float* __restrict__ Wo, f16* __restrict__ qh,
                          f16* __restrict__ wqhi, f16* __restrict__ wohi) {
    size_t i = ((size_t)blockIdx.x * 256 + threadIdx.x) * 8;
    const float* src;
    f16* dst;
    if (i < 16777216) { src = q + i; dst = qh + i; }
    else {
        size_t wi = i - 16777216;
        if (wi < 1048576) { src = Wq + wi; dst = wqhi + wi; }
        else              { src = Wo + (wi - 1048576); dst = wohi + (wi - 1048576); }
    }
    cvt8_hilo(src, dst, nullptr, false);
}

// ---------------------------------------------------------------------------
// Buffer plan (Mi = 1<<20 bytes; ws peak = 76Mi):
// ws:  0-8    Ghi (after XvTh dead)        32-48  G0 fp32 -> Wqhi@32, Wohi@34
//      8-16   Glo                          48-64  G1 fp32
//      16-24  A3hi (XvTh dead)             64-72  Wkhi|Wvhi|Wklo|Wvlo
//      24-32  A3lo                         36-68  att (after ctx done)
//      72Mi   ctxT (512Ki); +512Ki sk(16Ki) sv(16Ki) u(16Ki) w(16Ki)
//      XvTh = ws+0..32 (dead after gram1)
// d_out: XkTh 0-32 | XkTl->XvTl 32-64  ->  P0 0-16 | P1 16-32
//        -> qh 0-32 | qp 32-64 -> final fp32 out 0-64.
// ---------------------------------------------------------------------------
extern "C" void kernel_launch(void* const* d_in, const int* in_sizes, int n_in,
                              void* d_out, int out_size, void* d_ws, size_t ws_size,
                              hipStream_t stream) {
    const float* q  = (const float*)d_in[0];
    const float* k  = (const float*)d_in[1];
    const float* v  = (const float*)d_in[2];
    const float* Wq = (const float*)d_in[3];
    const float* bq = (const float*)d_in[4];
    const float* Wk = (const float*)d_in[5];
    const float* bk = (const float*)d_in[6];
    const float* Wv = (const float*)d_in[7];
    const float* bv = (const float*)d_in[8];
    const float* Wo = (const float*)d_in[9];

    const size_t Mi = 1048576;
    char* ws = (char*)d_ws;
    char* ob = (char*)d_out;

    f16*   Ghi  = (f16*)ws;                       // 0-8
    f16*   Glo  = (f16*)(ws + 8 * Mi);            // 8-16
    f16*   A3hi = (f16*)(ws + 16 * Mi);           // 16-24
    f16*   A3lo = (f16*)(ws + 24 * Mi);           // 24-32
    float* G0   = (float*)(ws + 32 * Mi);         // 32-48
    float* G1   = (float*)(ws + 48 * Mi);         // 48-64
    f16*   Wkhi = (f16*)(ws + 64 * Mi);
    f16*   Wvhi = (f16*)(ws + 66 * Mi);
    f16*   Wklo = (f16*)(ws + 68 * Mi);
    f16*   Wvlo = (f16*)(ws + 70 * Mi);
    f16*   ctxT = (f16*)(ws + 72 * Mi);           // 512 Ki
    float* sk   = (float*)(ws + 72 * Mi + 524288);
    float* sv   = (float*)(ws + 72 * Mi + 540672);
    float* u    = (float*)(ws + 72 * Mi + 557056);
    float* w    = (float*)(ws + 72 * Mi + 573440);
    f16*   XvTh = (f16*)ws;                       // 0-32, dead after gram1
    f16*   Wqhi = (f16*)(ws + 32 * Mi);           // after G0 dead
    f16*   Wohi = (f16*)(ws + 34 * Mi);
    f16*   att  = (f16*)(ws + 36 * Mi);           // 36-68, after ctx done

    f16*   XkTh = (f16*)ob;                       // 0-32
    f16*   XkTl = (f16*)(ob + 32 * Mi);
    f16*   XvTl = (f16*)(ob + 32 * Mi);           // after gram1
    float* P0   = (float*)ob;                     // 0-16, after gram2
    float* P1   = (float*)(ob + 16 * Mi);         // 16-32
    f16*   qh   = (f16*)ob;                       // after a3_combine
    f16*   qp   = (f16*)(ob + 32 * Mi);
    float* out  = (float*)d_out;

    // zero atomic colsum targets (sk|sv contiguous, 8192 floats)
    zero_f32<<<8, 256, 0, stream>>>(sk);
    // weights hi/lo for the high-precision ctx path
    cvt_w_kv<<<dim3(512, 2), 256, 0, stream>>>(Wk, Wv, Wkhi, Wvhi, Wklo, Wvlo);
    // transposed hi/lo inputs + fused column sums
    transpose_cvt<0, true><<<dim3(64, 16, 4), 256, 0, stream>>>(k, XkTh, XkTl, sk);
    transpose_cvt<1, true><<<dim3(64, 16, 4), 256, 0, stream>>>(v, XvTh, nullptr, sv);
    // G' = Xv^T Xk, double-f16: hi*(hi+lo) then + lo*hi  (z-first grids)
    gram_gemm<2, false><<<dim3(8, 8, 8), 256, 0, stream>>>(XvTh, XkTh, XkTl, G0, G1);
    transpose_cvt<2, false><<<dim3(64, 16, 4), 256, 0, stream>>>(v, XvTl, nullptr, nullptr);
    gram_gemm<1, true><<<dim3(8, 8, 8), 256, 0, stream>>>(XvTl, XkTh, nullptr, G0, G1);
    // G -> f16 hi/lo (coalesced), then all-f16 K-split a3, then combine
    combine_split<<<2048, 256, 0, stream>>>(G0, G1, Ghi, Glo);
    a3f16_gemm<<<dim3(8, 8, 8), 256, 0, stream>>>(Wkhi, Wklo, Ghi, Glo, P0, P1);
    combine_split<<<2048, 256, 0, stream>>>(P0, P1, A3hi, A3lo);
    // rank-1 bias terms
    bias_vec<<<dim3(1024, 2), 256, 0, stream>>>(sk, sv, Wk, Wv, u, w);
    // ctx + softmax -> ctxT
    ctx_gemm_softmax<<<64, 256, 0, stream>>>(A3hi, A3lo, Wvhi, Wvlo, u, w, bk, bv, ctxT);
    // Q path (f16 sufficient: feature softmax bounds sensitivity)
    cvt_q_wqo<<<9216, 256, 0, stream>>>(q, Wq, Wo, qh, Wqhi, Wohi);
    proj_qsm_gemm<<<dim3(128, 8), 256, 0, stream>>>(qh, Wqhi, bq, qp);
    att_gemm<<<dim3(128, 8), 256, 0, stream>>>(qp, ctxT, att);
    out_gemm<<<dim3(128, 8), 256, 0, stream>>>(att, Wohi, out);
}

// Round 6
// 596.953 us; speedup vs baseline: 1.2682x; 1.0003x over previous
//
#include <hip/hip_runtime.h>

#define INV_QTR 0.59460355750136053f   // 8^(-1/4)

typedef _Float16 f16;
typedef _Float16 f16x8 __attribute__((ext_vector_type(8)));
typedef float f32x4 __attribute__((ext_vector_type(4)));

__device__ __forceinline__ void gload16(const void* g, void* l) {
    __builtin_amdgcn_global_load_lds(
        (const __attribute__((address_space(1))) void*)g,
        (__attribute__((address_space(3))) void*)l, 16, 0, 0);
}

// ---------------------------------------------------------------------------
// All-f16 BT-GEMM (m97 structure): dst[m][n] = sum_k X[m][k]*W[n][k] (+bias).
// 128x128 tile, BK=64, global_load_lds width=16, XOR swizzle on 16B chunks,
// 16x16x32 f16 MFMA, fp32 accum.  (used by out_gemm)
// ---------------------------------------------------------------------------
template <bool OF, bool BIAS>
__device__ __forceinline__ void gemm_f16_body(const f16* __restrict__ X,
                                              const f16* __restrict__ W,
                                              const float* __restrict__ bias,
                                              void* __restrict__ dst) {
    __shared__ __align__(16) f16 As[128 * 64];
    __shared__ __align__(16) f16 Bs[128 * 64];

    const int tid  = threadIdx.x;
    const int lane = tid & 63;
    const int wave = tid >> 6;
    const int m0   = blockIdx.x * 128;
    const int n0   = blockIdx.y * 128;
    const int wm   = (wave >> 1) * 64;
    const int wn   = (wave & 1) * 64;
    const int frow = lane & 15;
    const int quad = lane >> 4;

    f32x4 acc[4][4] = {};

    for (int k0 = 0; k0 < 1024; k0 += 64) {
        __syncthreads();
        #pragma unroll
        for (int i = 0; i < 4; ++i) {
            int slot = i * 256 + tid;
            int row  = slot >> 3;
            int sc   = slot & 7;
            int gc   = sc ^ (row & 7);
            gload16(X + (size_t)(m0 + row) * 1024 + k0 + gc * 8,
                    (char*)As + slot * 16);
            gload16(W + (size_t)(n0 + row) * 1024 + k0 + gc * 8,
                    (char*)Bs + slot * 16);
        }
        __syncthreads();

        #pragma unroll
        for (int kk = 0; kk < 2; ++kk) {
            f16x8 fa[4], fb[4];
            #pragma unroll
            for (int t = 0; t < 4; ++t) {
                int arow = wm + t * 16 + frow;
                int asc  = (kk * 4 + quad) ^ (arow & 7);
                fa[t] = *(const f16x8*)(As + arow * 64 + asc * 8);
                int brow = wn + t * 16 + frow;
                int bsc  = (kk * 4 + quad) ^ (brow & 7);
                fb[t] = *(const f16x8*)(Bs + brow * 64 + bsc * 8);
            }
            #pragma unroll
            for (int tm = 0; tm < 4; ++tm)
                #pragma unroll
                for (int tn = 0; tn < 4; ++tn)
                    acc[tm][tn] = __builtin_amdgcn_mfma_f32_16x16x32_f16(
                        fa[tm], fb[tn], acc[tm][tn], 0, 0, 0);
        }
    }

    #pragma unroll
    for (int tn = 0; tn < 4; ++tn) {
        int col = n0 + wn + tn * 16 + frow;
        float badd = BIAS ? bias[col] : 0.0f;
        #pragma unroll
        for (int tm = 0; tm < 4; ++tm) {
            #pragma unroll
            for (int r = 0; r < 4; ++r) {
                size_t idx = (size_t)(m0 + wm + tm * 16 + quad * 4 + r) * 1024 + col;
                float v = acc[tm][tn][r] + badd;
                if (OF) ((float*)dst)[idx] = v;
                else    ((f16*)dst)[idx] = (f16)v;
            }
        }
    }
}

// out = att @ Wo^T (no bias), fp32 out.  grid (128, 8).
__global__ void out_gemm(const f16* __restrict__ att, const f16* __restrict__ Wo,
                         float* __restrict__ out) {
    gemm_f16_body<true, false>(att, Wo, nullptr, out);
}

// ---------------------------------------------------------------------------
// Transpose + fp32->f16 hi/lo split body: src [4][4096][1024] f32 ->
// dstT [4][1024][4096].  MODE 0: hi+lo.  MODE 1: hi.  MODE 2: lo.
// CS: per-block column-sum partial (plain store, no atomics):
//   csum[(b*1024+c)*64 + n-chunk] = sum over this block's 64 n.
// ---------------------------------------------------------------------------
template <int MODE, bool CS>
__device__ __forceinline__ void transpose_body(const float* __restrict__ src,
                                               f16* __restrict__ dst0,
                                               f16* __restrict__ dst1,
                                               float* __restrict__ csum,
                                               int bx, int by, int bz,
                                               float (*T)[65]) {
    int n0 = bx * 64, c0 = by * 64, b = bz;
    int tid = threadIdx.x;
    const float* s = src + ((size_t)b * 4096 + n0) * 1024 + c0;
    int r = tid >> 2, q4 = tid & 3;
    #pragma unroll
    for (int i = 0; i < 4; ++i) {
        f32x4 v = *(const f32x4*)(s + (size_t)r * 1024 + q4 * 16 + i * 4);
        #pragma unroll
        for (int j = 0; j < 4; ++j) T[q4 * 16 + i * 4 + j][r] = v[j];
    }
    __syncthreads();
    int cc = tid >> 2, nq = tid & 3;
    size_t obase = ((size_t)b * 1024 + c0 + cc) * 4096 + n0 + nq * 16;
    float x[16];
    #pragma unroll
    for (int j = 0; j < 16; ++j) x[j] = T[cc][nq * 16 + j];
    if (CS) {
        float ssum = 0.f;
        #pragma unroll
        for (int j = 0; j < 16; ++j) ssum += x[j];
        ssum += __shfl_xor(ssum, 1, 64);
        ssum += __shfl_xor(ssum, 2, 64);
        if (nq == 0) csum[((size_t)(b * 1024 + c0 + cc)) * 64 + bx] = ssum;
    }
    f16x8 hi0, hi1;
    #pragma unroll
    for (int j = 0; j < 8; ++j) { hi0[j] = (f16)x[j]; hi1[j] = (f16)x[8 + j]; }
    if (MODE == 0 || MODE == 1) {
        *(f16x8*)(dst0 + obase) = hi0;
        *(f16x8*)(dst0 + obase + 8) = hi1;
    }
    if (MODE == 0 || MODE == 2) {
        f16x8 lo0, lo1;
        #pragma unroll
        for (int j = 0; j < 8; ++j) {
            lo0[j] = (f16)(x[j] - (float)hi0[j]);
            lo1[j] = (f16)(x[8 + j] - (float)hi1[j]);
        }
        f16* d = (MODE == 0) ? dst1 : dst0;
        *(f16x8*)(d + obase) = lo0;
        *(f16x8*)(d + obase + 8) = lo1;
    }
}

__device__ __forceinline__ void cvt8_hilo(const float* src, f16* dh, f16* dl, bool lo) {
    f32x4 a = ((const f32x4*)src)[0];
    f32x4 b = ((const f32x4*)src)[1];
    f16x8 h, l;
    #pragma unroll
    for (int j = 0; j < 4; ++j) {
        h[j] = (f16)a[j];     h[j + 4] = (f16)b[j];
        l[j] = (f16)(a[j] - (float)h[j]);
        l[j + 4] = (f16)(b[j] - (float)h[j + 4]);
    }
    *(f16x8*)dh = h;
    if (lo) *(f16x8*)dl = l;
}

// ---------------------------------------------------------------------------
// prep: transpose k (MODE0+CS) | transpose v (MODE1+CS) | cvt Wk/Wv hi+lo.
// grid 9216 flat: [0,4096) tk, [4096,8192) tv, [8192,9216) cvt_w.
// ---------------------------------------------------------------------------
__global__ void prep_kernel(const float* __restrict__ k, const float* __restrict__ v,
                            const float* __restrict__ Wk, const float* __restrict__ Wv,
                            f16* __restrict__ XkTh, f16* __restrict__ XkTl,
                            f16* __restrict__ XvTh,
                            f16* __restrict__ whik, f16* __restrict__ whiv,
                            f16* __restrict__ wlok, f16* __restrict__ wlov,
                            float* __restrict__ pk, float* __restrict__ pv) {
    __shared__ float T[64][65];
    int bid = blockIdx.x;
    if (bid < 4096) {
        transpose_body<0, true>(k, XkTh, XkTl, pk, bid & 63, (bid >> 6) & 15,
                                bid >> 10, T);
    } else if (bid < 8192) {
        int g = bid - 4096;
        transpose_body<1, true>(v, XvTh, nullptr, pv, g & 63, (g >> 6) & 15,
                                g >> 10, T);
    } else {
        int g = bid - 8192;                       // 0..1023
        const float* s = (g >= 512) ? Wv : Wk;
        f16* dh = (g >= 512) ? whiv : whik;
        f16* dl = (g >= 512) ? wlov : wlok;
        size_t i = ((size_t)(g & 511) * 256 + threadIdx.x) * 8;
        cvt8_hilo(s + i, dh + i, dl + i, true);
    }
}

// ---------------------------------------------------------------------------
// tvlo: transpose v lo (MODE2) | reduce colsum partials -> sk, sv.
// grid 4128 flat: [0,4096) tv-lo, [4096,4128) reduce (8192 outputs).
// ---------------------------------------------------------------------------
__global__ void tvlo_kernel(const float* __restrict__ v, f16* __restrict__ XvTl,
                            const float* __restrict__ pk, const float* __restrict__ pv,
                            float* __restrict__ sk, float* __restrict__ sv) {
    __shared__ float T[64][65];
    int bid = blockIdx.x;
    if (bid < 4096) {
        transpose_body<2, false>(v, XvTl, nullptr, nullptr, bid & 63,
                                 (bid >> 6) & 15, bid >> 10, T);
    } else {
        int idx = (bid - 4096) * 256 + threadIdx.x;   // 0..8191
        const float* p = (idx < 4096) ? pk : pv;
        float* d = (idx < 4096) ? sk : sv;
        int c = idx & 4095;
        float s = 0.f;
        #pragma unroll
        for (int ch = 0; ch < 64; ++ch) s += p[(size_t)c * 64 + ch];
        d[c] = s;
    }
}

// ---------------------------------------------------------------------------
// Gram GEMM: G'[p][q] = sum_n XvT[p][n]*XkT[q][n].  z-first XCD clustering:
// grid (8 zsel, 8 m, 8 n), zsel = b*2 + khalf on blockIdx.x.
// NB==2: acc += A*(B0+B1);  ACCUM: RMW fp32 out.
// ---------------------------------------------------------------------------
template <int NB, bool ACCUM>
__global__ void gram_gemm(const f16* __restrict__ A, const f16* __restrict__ B0,
                          const f16* __restrict__ B1, float* __restrict__ G0,
                          float* __restrict__ G1) {
    __shared__ __align__(16) f16 As[128 * 64];
    __shared__ __align__(16) f16 Bs0[128 * 64];
    __shared__ __align__(16) f16 Bs1[NB == 2 ? 128 * 64 : 8];
    const int tid = threadIdx.x, lane = tid & 63, wave = tid >> 6;
    const int zsel = blockIdx.x;
    const int m0 = blockIdx.y * 128, n0 = blockIdx.z * 128;
    const int b = zsel >> 1, kh = zsel & 1;
    const int wm = (wave >> 1) * 64, wn = (wave & 1) * 64;
    const int frow = lane & 15, quad = lane >> 4;
    const f16* Ab  = A + (size_t)b * 4194304;
    const f16* B0b = B0 + (size_t)b * 4194304;
    const f16* B1b = (NB == 2) ? B1 + (size_t)b * 4194304 : nullptr;
    float* Gd = (kh ? G1 : G0) + (size_t)b * 1048576;
    const int kbase = kh * 2048;
    f32x4 acc[4][4] = {};

    for (int k0 = kbase; k0 < kbase + 2048; k0 += 64) {
        __syncthreads();
        #pragma unroll
        for (int i = 0; i < 4; ++i) {
            int slot = i * 256 + tid, row = slot >> 3, sc = slot & 7;
            int gc = sc ^ (row & 7);
            gload16(Ab + (size_t)(m0 + row) * 4096 + k0 + gc * 8, (char*)As + slot * 16);
            gload16(B0b + (size_t)(n0 + row) * 4096 + k0 + gc * 8, (char*)Bs0 + slot * 16);
            if (NB == 2)
                gload16(B1b + (size_t)(n0 + row) * 4096 + k0 + gc * 8, (char*)Bs1 + slot * 16);
        }
        __syncthreads();
        #pragma unroll
        for (int kk = 0; kk < 2; ++kk) {
            f16x8 fa[4], fb0[4], fb1[4];
            #pragma unroll
            for (int t = 0; t < 4; ++t) {
                int arow = wm + t * 16 + frow;
                int asc  = (kk * 4 + quad) ^ (arow & 7);
                fa[t] = *(const f16x8*)(As + arow * 64 + asc * 8);
                int brow = wn + t * 16 + frow;
                int bsc  = (kk * 4 + quad) ^ (brow & 7);
                fb0[t] = *(const f16x8*)(Bs0 + brow * 64 + bsc * 8);
                if (NB == 2) fb1[t] = *(const f16x8*)(Bs1 + brow * 64 + bsc * 8);
            }
            #pragma unroll
            for (int tm = 0; tm < 4; ++tm)
                #pragma unroll
                for (int tn = 0; tn < 4; ++tn) {
                    acc[tm][tn] = __builtin_amdgcn_mfma_f32_16x16x32_f16(
                        fa[tm], fb0[tn], acc[tm][tn], 0, 0, 0);
                    if (NB == 2)
                        acc[tm][tn] = __builtin_amdgcn_mfma_f32_16x16x32_f16(
                            fa[tm], fb1[tn], acc[tm][tn], 0, 0, 0);
                }
        }
    }
    #pragma unroll
    for (int tn = 0; tn < 4; ++tn) {
        int col = n0 + wn + tn * 16 + frow;
        #pragma unroll
        for (int tm = 0; tm < 4; ++tm)
            #pragma unroll
            for (int r = 0; r < 4; ++r) {
                size_t idx = (size_t)(m0 + wm + tm * 16 + quad * 4 + r) * 1024 + col;
                if (ACCUM) Gd[idx] += acc[tm][tn][r];
                else       Gd[idx]  = acc[tm][tn][r];
            }
    }
}

// ---------------------------------------------------------------------------
// mid: combine_split(G0+G1 -> Ghi/Glo) | bias_vec (u=Wk@sk, w=Wv@sv).
// grid 4096 flat: [0,2048) combine, [2048,4096) bias.
// ---------------------------------------------------------------------------
__global__ void mid_kernel(const float* __restrict__ G0, const float* __restrict__ G1,
                           f16* __restrict__ Ghi, f16* __restrict__ Glo,
                           const float* __restrict__ sk, const float* __restrict__ sv,
                           const float* __restrict__ Wk, const float* __restrict__ Wv,
                           float* __restrict__ u, float* __restrict__ w) {
    int bid = blockIdx.x;
    if (bid < 2048) {
        size_t i = ((size_t)bid * 256 + threadIdx.x) * 8;
        f32x4 a0 = *(const f32x4*)(G0 + i);
        f32x4 a1 = *(const f32x4*)(G0 + i + 4);
        f32x4 b0 = *(const f32x4*)(G1 + i);
        f32x4 b1 = *(const f32x4*)(G1 + i + 4);
        f16x8 h, l;
        #pragma unroll
        for (int j = 0; j < 4; ++j) {
            float s0 = a0[j] + b0[j], s1 = a1[j] + b1[j];
            h[j] = (f16)s0;     l[j] = (f16)(s0 - (float)h[j]);
            h[4 + j] = (f16)s1; l[4 + j] = (f16)(s1 - (float)h[4 + j]);
        }
        *(f16x8*)(Ghi + i) = h;
        *(f16x8*)(Glo + i) = l;
    } else {
        int g = bid - 2048;
        int yy = g >> 10;                             // 0: k, 1: v
        int gid = (g & 1023) * 4 + (threadIdx.x >> 6);
        int lane = threadIdx.x & 63;
        int b = gid >> 10, d = gid & 1023;
        const float* W = yy ? Wv : Wk;
        const float* s = yy ? sv : sk;
        float* dst = yy ? w : u;
        const float* wr = W + (size_t)d * 1024;
        const float* sr = s + b * 1024;
        float acc = 0.f;
        #pragma unroll
        for (int t = 0; t < 16; ++t) acc += wr[lane + t * 64] * sr[lane + t * 64];
        #pragma unroll
        for (int s2 = 32; s2; s2 >>= 1) acc += __shfl_xor(acc, s2, 64);
        if (lane == 0) dst[b * 1024 + d] = acc;
    }
}

// ---------------------------------------------------------------------------
// a3 = Wk @ G' (3-term double-f16).  Grid (8 zsel, 8 m, 8 n), zsel = b*2+kh.
// Writes fp32 partials P0/P1; no RMW.
// ---------------------------------------------------------------------------
__global__ void a3f16_gemm(const f16* __restrict__ wkhi, const f16* __restrict__ wklo,
                           const f16* __restrict__ ghi, const f16* __restrict__ glo,
                           float* __restrict__ P0, float* __restrict__ P1) {
    __shared__ __align__(16) f16 As0[128 * 64], As1[128 * 64];
    __shared__ __align__(16) f16 Bs0[128 * 64], Bs1[128 * 64];
    const int tid = threadIdx.x, lane = tid & 63, wave = tid >> 6;
    const int zsel = blockIdx.x;
    const int m0 = blockIdx.y * 128, n0 = blockIdx.z * 128;
    const int b = zsel >> 1, kh = zsel & 1;
    const int wm = (wave >> 1) * 64, wn = (wave & 1) * 64;
    const int frow = lane & 15, quad = lane >> 4;
    const f16* g0b = ghi + (size_t)b * 1048576;
    const f16* g1b = glo + (size_t)b * 1048576;
    float* Pd = (kh ? P1 : P0) + (size_t)b * 1048576;
    const int kbase = kh * 512;
    f32x4 acc[4][4] = {};

    for (int k0 = kbase; k0 < kbase + 512; k0 += 64) {
        __syncthreads();
        #pragma unroll
        for (int i = 0; i < 4; ++i) {
            int slot = i * 256 + tid, row = slot >> 3, sc = slot & 7;
            int gc = sc ^ (row & 7);
            size_t ao = (size_t)(m0 + row) * 1024 + k0 + gc * 8;
            size_t bo = (size_t)(n0 + row) * 1024 + k0 + gc * 8;
            gload16(wkhi + ao, (char*)As0 + slot * 16);
            gload16(wklo + ao, (char*)As1 + slot * 16);
            gload16(g0b + bo, (char*)Bs0 + slot * 16);
            gload16(g1b + bo, (char*)Bs1 + slot * 16);
        }
        __syncthreads();
        #pragma unroll
        for (int kk = 0; kk < 2; ++kk) {
            f16x8 fa0[4], fa1[4], fb0[4], fb1[4];
            #pragma unroll
            for (int t = 0; t < 4; ++t) {
                int arow = wm + t * 16 + frow;
                int asc  = (kk * 4 + quad) ^ (arow & 7);
                fa0[t] = *(const f16x8*)(As0 + arow * 64 + asc * 8);
                fa1[t] = *(const f16x8*)(As1 + arow * 64 + asc * 8);
                int brow = wn + t * 16 + frow;
                int bsc  = (kk * 4 + quad) ^ (brow & 7);
                fb0[t] = *(const f16x8*)(Bs0 + brow * 64 + bsc * 8);
                fb1[t] = *(const f16x8*)(Bs1 + brow * 64 + bsc * 8);
            }
            #pragma unroll
            for (int tm = 0; tm < 4; ++tm)
                #pragma unroll
                for (int tn = 0; tn < 4; ++tn) {
                    acc[tm][tn] = __builtin_amdgcn_mfma_f32_16x16x32_f16(
                        fa0[tm], fb0[tn], acc[tm][tn], 0, 0, 0);
                    acc[tm][tn] = __builtin_amdgcn_mfma_f32_16x16x32_f16(
                        fa1[tm], fb0[tn], acc[tm][tn], 0, 0, 0);
                    acc[tm][tn] = __builtin_amdgcn_mfma_f32_16x16x32_f16(
                        fa0[tm], fb1[tn], acc[tm][tn], 0, 0, 0);
                }
        }
    }
    #pragma unroll
    for (int tn = 0; tn < 4; ++tn) {
        int col = n0 + wn + tn * 16 + frow;
        #pragma unroll
        for (int tm = 0; tm < 4; ++tm)
            #pragma unroll
            for (int r = 0; r < 4; ++r)
                Pd[(size_t)(m0 + wm + tm * 16 + quad * 4 + r) * 1024 + col] =
                    acc[tm][tn][r];
    }
}

// ---------------------------------------------------------------------------
// ctx per head from fp32 partials: A = (P0+P1) split hi/lo inline (reg-staged,
// same swizzled LDS layout), B = Wv hi/lo via gload_lds.  3-term MFMA,
// + rank-1 bias terms; softmax over dd; *INV_QTR; store ctxT[bh][ee][dd] f16.
// grid (64).
// ---------------------------------------------------------------------------
__global__ void ctx_ps(const float* __restrict__ P0, const float* __restrict__ P1,
                       const f16* __restrict__ wvhi, const f16* __restrict__ wvlo,
                       const float* __restrict__ u, const float* __restrict__ wvec,
                       const float* __restrict__ bk, const float* __restrict__ bv,
                       f16* __restrict__ ctxT) {
    __shared__ __align__(16) f16 As0[64 * 64], As1[64 * 64], Bs0[64 * 64], Bs1[64 * 64];
    __shared__ float cs[64 * 65];
    int bh = blockIdx.x, b = bh >> 4, h = bh & 15;
    int tid = threadIdx.x, lane = tid & 63, wave = tid >> 6;
    const float* p0b = P0 + (size_t)b * 1048576 + (size_t)(h * 64) * 1024;
    const float* p1b = P1 + (size_t)b * 1048576 + (size_t)(h * 64) * 1024;
    const size_t wbase = (size_t)(h * 64) * 1024;
    int frow = lane & 15, quad = lane >> 4;
    f32x4 acc[4] = {};

    for (int k0 = 0; k0 < 1024; k0 += 64) {
        __syncthreads();
        #pragma unroll
        for (int i = 0; i < 2; ++i) {
            int slot = i * 256 + tid, row = slot >> 3, sc = slot & 7;
            int gc = sc ^ (row & 7);
            size_t ro = (size_t)row * 1024 + k0 + gc * 8;
            // A: fp32 partial sum -> hi/lo split -> LDS (reg-staged)
            f32x4 xa = *(const f32x4*)(p0b + ro);
            f32x4 xb = *(const f32x4*)(p0b + ro + 4);
            f32x4 ya = *(const f32x4*)(p1b + ro);
            f32x4 yb = *(const f32x4*)(p1b + ro + 4);
            f16x8 hh, ll;
            #pragma unroll
            for (int j = 0; j < 4; ++j) {
                float s0 = xa[j] + ya[j], s1 = xb[j] + yb[j];
                hh[j] = (f16)s0;     ll[j] = (f16)(s0 - (float)hh[j]);
                hh[4 + j] = (f16)s1; ll[4 + j] = (f16)(s1 - (float)hh[4 + j]);
            }
            *(f16x8*)((char*)As0 + slot * 16) = hh;
            *(f16x8*)((char*)As1 + slot * 16) = ll;
            // B: Wv hi/lo direct to LDS
            gload16(wvhi + wbase + ro, (char*)Bs0 + slot * 16);
            gload16(wvlo + wbase + ro, (char*)Bs1 + slot * 16);
        }
        __syncthreads();
        #pragma unroll
        for (int kk = 0; kk < 2; ++kk) {
            int arow = wave * 16 + frow;
            int asc  = (kk * 4 + quad) ^ (arow & 7);
            f16x8 fa0 = *(const f16x8*)(As0 + arow * 64 + asc * 8);
            f16x8 fa1 = *(const f16x8*)(As1 + arow * 64 + asc * 8);
            #pragma unroll
            for (int tn = 0; tn < 4; ++tn) {
                int brow = tn * 16 + frow;
                int bsc  = (kk * 4 + quad) ^ (brow & 7);
                f16x8 fb0 = *(const f16x8*)(Bs0 + brow * 64 + bsc * 8);
                f16x8 fb1 = *(const f16x8*)(Bs1 + brow * 64 + bsc * 8);
                acc[tn] = __builtin_amdgcn_mfma_f32_16x16x32_f16(fa0, fb0, acc[tn], 0, 0, 0);
                acc[tn] = __builtin_amdgcn_mfma_f32_16x16x32_f16(fa1, fb0, acc[tn], 0, 0, 0);
                acc[tn] = __builtin_amdgcn_mfma_f32_16x16x32_f16(fa0, fb1, acc[tn], 0, 0, 0);
            }
        }
    }

    const float* ub  = u + b * 1024 + h * 64;
    const float* wb  = wvec + b * 1024 + h * 64;
    const float* bkh = bk + h * 64;
    const float* bvh = bv + h * 64;
    #pragma unroll
    for (int tn = 0; tn < 4; ++tn) {
        int ee = tn * 16 + frow;
        float bve = bvh[ee], we = wb[ee];
        #pragma unroll
        for (int r = 0; r < 4; ++r) {
            int dd = wave * 16 + quad * 4 + r;
            float bkd = bkh[dd], ud = ub[dd];
            cs[dd * 65 + ee] = acc[tn][r] + bkd * we + bve * ud + 4096.0f * bkd * bve;
        }
    }
    __syncthreads();
    #pragma unroll
    for (int i = 0; i < 16; ++i) {
        int e = wave * 16 + i;
        float x = cs[lane * 65 + e];
        float m = x;
        #pragma unroll
        for (int s2 = 32; s2; s2 >>= 1) m = fmaxf(m, __shfl_xor(m, s2, 64));
        float ex = __expf(x - m);
        float sum = ex;
        #pragma unroll
        for (int s2 = 32; s2; s2 >>= 1) sum += __shfl_xor(sum, s2, 64);
        ctxT[((size_t)bh * 64 + e) * 64 + lane] = (f16)(ex / sum * INV_QTR);
    }
}

// ---------------------------------------------------------------------------
// q -> f16; Wq, Wo -> hi f16.  grid (9216).
// ---------------------------------------------------------------------------
__global__ void cvt_q_wqo(const float* __restrict__ q, const float* __restrict__ Wq,
                          const float* __restrict__ Wo, f16* __restrict__ qh,
                          f16* __restrict__ wqhi, f16* __restrict__ wohi) {
    size_t i = ((size_t)blockIdx.x * 256 + threadIdx.x) * 8;
    const float* src;
    f16* dst;
    if (i < 16777216) { src = q + i; dst = qh + i; }
    else {
        size_t wi = i - 16777216;
        if (wi < 1048576) { src = Wq + wi; dst = wqhi + wi; }
        else              { src = Wo + (wi - 1048576); dst = wohi + (wi - 1048576); }
    }
    cvt8_hilo(src, dst, nullptr, false);
}

// ---------------------------------------------------------------------------
// proj_att: Q projection (m97 GEMM) + fused feature-softmax -> qs in LDS
// (136-f16 padded rows, 16B aligned) -> att = qs @ ctx (block-diag K=64).
// grid (128, 8), 256 threads, LDS 50 KB -> 3 blocks/CU.
// ---------------------------------------------------------------------------
__global__ void __launch_bounds__(256)
proj_att(const f16* __restrict__ qh, const f16* __restrict__ Wqhi,
         const float* __restrict__ bias, const f16* __restrict__ ctxT,
         f16* __restrict__ att) {
    __shared__ __align__(16) char SMEM[34816];     // As|Bs during GEMM; qsS after
    __shared__ __align__(16) f16 ctxS[2][4096];
    f16* As  = (f16*)SMEM;
    f16* Bs  = (f16*)(SMEM + 16384);
    f16* qsS = (f16*)SMEM;                          // [128][136]

    const int tid  = threadIdx.x;
    const int lane = tid & 63;
    const int wave = tid >> 6;
    const int m0   = blockIdx.x * 128;
    const int n0   = blockIdx.y * 128;
    const int wm   = (wave >> 1) * 64;
    const int wn   = (wave & 1) * 64;               // head offset within tile
    const int frow = lane & 15;
    const int quad = lane >> 4;
    const int b    = m0 >> 12;
    const int h0   = (n0 >> 6) & 15;

    // stage ctxT for both heads early (consumed after the K-loop)
    #pragma unroll
    for (int ch = 0; ch < 2; ++ch)
        #pragma unroll
        for (int i = 0; i < 2; ++i) {
            int slot = i * 256 + tid, row = slot >> 3, gc = (slot & 7) ^ (row & 7);
            int bh = b * 16 + h0 + ch;
            gload16(ctxT + ((size_t)bh * 64 + row) * 64 + gc * 8,
                    (char*)ctxS[ch] + slot * 16);
        }

    f32x4 acc[4][4] = {};
    for (int k0 = 0; k0 < 1024; k0 += 64) {
        __syncthreads();
        #pragma unroll
        for (int i = 0; i < 4; ++i) {
            int slot = i * 256 + tid, row = slot >> 3, sc = slot & 7;
            int gc = sc ^ (row & 7);
            gload16(qh + (size_t)(m0 + row) * 1024 + k0 + gc * 8,
                    (char*)As + slot * 16);
            gload16(Wqhi + (size_t)(n0 + row) * 1024 + k0 + gc * 8,
                    (char*)Bs + slot * 16);
        }
        __syncthreads();
        #pragma unroll
        for (int kk = 0; kk < 2; ++kk) {
            f16x8 fa[4], fb[4];
            #pragma unroll
            for (int t = 0; t < 4; ++t) {
                int arow = wm + t * 16 + frow;
                int asc  = (kk * 4 + quad) ^ (arow & 7);
                fa[t] = *(const f16x8*)(As + arow * 64 + asc * 8);
                int brow = wn + t * 16 + frow;
                int bsc  = (kk * 4 + quad) ^ (brow & 7);
                fb[t] = *(const f16x8*)(Bs + brow * 64 + bsc * 8);
            }
            #pragma unroll
            for (int tm = 0; tm < 4; ++tm)
                #pragma unroll
                for (int tn = 0; tn < 4; ++tn)
                    acc[tm][tn] = __builtin_amdgcn_mfma_f32_16x16x32_f16(
                        fa[tm], fb[tn], acc[tm][tn], 0, 0, 0);
        }
    }
    __syncthreads();    // all waves done reading As/Bs before qsS overwrite

    // feature-softmax over the 64-wide head group -> qs in LDS (f16)
    float badd[4];
    #pragma unroll
    for (int tn = 0; tn < 4; ++tn) badd[tn] = bias[n0 + wn + tn * 16 + frow];
    #pragma unroll
    for (int tm = 0; tm < 4; ++tm) {
        #pragma unroll
        for (int r = 0; r < 4; ++r) {
            float x[4], m = -1e30f;
            #pragma unroll
            for (int tn = 0; tn < 4; ++tn) {
                x[tn] = acc[tm][tn][r] + badd[tn];
                m = fmaxf(m, x[tn]);
            }
            #pragma unroll
            for (int s = 1; s < 16; s <<= 1) m = fmaxf(m, __shfl_xor(m, s, 64));
            float e[4], sum = 0.f;
            #pragma unroll
            for (int tn = 0; tn < 4; ++tn) { e[tn] = __expf(x[tn] - m); sum += e[tn]; }
            #pragma unroll
            for (int s = 1; s < 16; s <<= 1) sum += __shfl_xor(sum, s, 64);
            float inv = INV_QTR / sum;
            int lrow = wm + tm * 16 + quad * 4 + r;
            #pragma unroll
            for (int tn = 0; tn < 4; ++tn)
                qsS[lrow * 136 + wn + tn * 16 + frow] = (f16)(e[tn] * inv);
        }
    }
    __syncthreads();

    // att = qs @ ctx for this head pair (K=64 per head)
    f32x4 a2[4][4] = {};
    const int chh = wave & 1;
    #pragma unroll
    for (int kk = 0; kk < 2; ++kk) {
        f16x8 fa[4], fb[4];
        #pragma unroll
        for (int t = 0; t < 4; ++t) {
            int arow = wm + t * 16 + frow;
            fa[t] = *(const f16x8*)(qsS + arow * 136 + wn + (kk * 4 + quad) * 8);
            int brow = t * 16 + frow;
            int bsc  = (kk * 4 + quad) ^ (brow & 7);
            fb[t] = *(const f16x8*)(ctxS[chh] + brow * 64 + bsc * 8);
        }
        #pragma unroll
        for (int tm = 0; tm < 4; ++tm)
            #pragma unroll
            for (int tn = 0; tn < 4; ++tn)
                a2[tm][tn] = __builtin_amdgcn_mfma_f32_16x16x32_f16(
                    fa[tm], fb[tn], a2[tm][tn], 0, 0, 0);
    }
    #pragma unroll
    for (int tn = 0; tn < 4; ++tn) {
        int col = n0 + wn + tn * 16 + frow;
        #pragma unroll
        for (int tm = 0; tm < 4; ++tm) {
            #pragma unroll
            for (int r = 0; r < 4; ++r) {
                int row = m0 + wm + tm * 16 + quad * 4 + r;
                att[(size_t)row * 1024 + col] = (f16)a2[tm][tn][r];
            }
        }
    }
}

// ---------------------------------------------------------------------------
// Buffer plan (Mi = 1<<20 bytes; ws peak < 76Mi):
// ws:  0-8    Ghi (after XvTh dead)        32-48  G0 fp32 -> Wqhi@32, Wohi@34
//      8-16   Glo                          48-64  G1 fp32
//      XvTh = ws+0..32 (dead after gram1)  64-72  Wkhi|Wvhi|Wklo|Wvlo
//      att 36-68 (after ctx done; Wk/Wv hi dead)
//      72Mi ctxT(512K) | 72.5 pk(1M) | 73.5 pv(1M) | 74.5 sk,sv,u,w(64K)
// d_out: XkTh 0-32 | XkTl->XvTl 32-64  ->  P0 0-16 | P1 16-32
//        -> qh 0-32 -> final fp32 out 0-64.
// ---------------------------------------------------------------------------
extern "C" void kernel_launch(void* const* d_in, const int* in_sizes, int n_in,
                              void* d_out, int out_size, void* d_ws, size_t ws_size,
                              hipStream_t stream) {
    const float* q  = (const float*)d_in[0];
    const float* k  = (const float*)d_in[1];
    const float* v  = (const float*)d_in[2];
    const float* Wq = (const float*)d_in[3];
    const float* bq = (const float*)d_in[4];
    const float* Wk = (const float*)d_in[5];
    const float* bk = (const float*)d_in[6];
    const float* Wv = (const float*)d_in[7];
    const float* bv = (const float*)d_in[8];
    const float* Wo = (const float*)d_in[9];

    const size_t Mi = 1048576;
    char* ws = (char*)d_ws;
    char* ob = (char*)d_out;

    f16*   Ghi  = (f16*)ws;                       // 0-8
    f16*   Glo  = (f16*)(ws + 8 * Mi);            // 8-16
    float* G0   = (float*)(ws + 32 * Mi);         // 32-48
    float* G1   = (float*)(ws + 48 * Mi);         // 48-64
    f16*   Wkhi = (f16*)(ws + 64 * Mi);
    f16*   Wvhi = (f16*)(ws + 66 * Mi);
    f16*   Wklo = (f16*)(ws + 68 * Mi);
    f16*   Wvlo = (f16*)(ws + 70 * Mi);
    f16*   ctxT = (f16*)(ws + 72 * Mi);           // 512 Ki
    float* pk   = (float*)(ws + 72 * Mi + 524288);   // 1 Mi
    float* pv   = (float*)(ws + 72 * Mi + 1572864);  // 1 Mi
    float* sk   = (float*)(ws + 72 * Mi + 2621440);
    float* sv   = (float*)(ws + 72 * Mi + 2637824);
    float* u    = (float*)(ws + 72 * Mi + 2654208);
    float* w    = (float*)(ws + 72 * Mi + 2670592);
    f16*   XvTh = (f16*)ws;                       // 0-32, dead after gram1
    f16*   Wqhi = (f16*)(ws + 32 * Mi);           // after G0 dead
    f16*   Wohi = (f16*)(ws + 34 * Mi);
    f16*   att  = (f16*)(ws + 36 * Mi);           // 36-68, after ctx done

    f16*   XkTh = (f16*)ob;                       // 0-32
    f16*   XkTl = (f16*)(ob + 32 * Mi);
    f16*   XvTl = (f16*)(ob + 32 * Mi);           // after gram2
    float* P0   = (float*)ob;                     // 0-16, after gram1
    float* P1   = (float*)(ob + 16 * Mi);         // 16-32
    f16*   qh   = (f16*)ob;                       // after ctx consumed P0/P1
    float* out  = (float*)d_out;

    // prep: transposes (k hi+lo, v hi) + colsum partials + Wk/Wv hi/lo
    prep_kernel<<<9216, 256, 0, stream>>>(k, v, Wk, Wv, XkTh, XkTl, XvTh,
                                          Wkhi, Wvhi, Wklo, Wvlo, pk, pv);
    // G' = Xv^T Xk, double-f16: hi*(hi+lo) then + lo*hi  (z-first grids)
    gram_gemm<2, false><<<dim3(8, 8, 8), 256, 0, stream>>>(XvTh, XkTh, XkTl, G0, G1);
    // v lo transpose + colsum reduce
    tvlo_kernel<<<4128, 256, 0, stream>>>(v, XvTl, pk, pv, sk, sv);
    gram_gemm<1, true><<<dim3(8, 8, 8), 256, 0, stream>>>(XvTl, XkTh, nullptr, G0, G1);
    // combine G -> f16 hi/lo + bias vectors
    mid_kernel<<<4096, 256, 0, stream>>>(G0, G1, Ghi, Glo, sk, sv, Wk, Wv, u, w);
    // a3 = Wk @ G (K-split fp32 partials)
    a3f16_gemm<<<dim3(8, 8, 8), 256, 0, stream>>>(Wkhi, Wklo, Ghi, Glo, P0, P1);
    // ctx + softmax -> ctxT  (reads P0/P1 fp32 directly)
    ctx_ps<<<64, 256, 0, stream>>>(P0, P1, Wvhi, Wvlo, u, w, bk, bv, ctxT);
    // Q path
    cvt_q_wqo<<<9216, 256, 0, stream>>>(q, Wq, Wo, qh, Wqhi, Wohi);
    proj_att<<<dim3(128, 8), 256, 0, stream>>>(qh, Wqhi, bq, ctxT, att);
    out_gemm<<<dim3(128, 8), 256, 0, stream>>>(att, Wohi, out);
}